// Round 1
// baseline (3151.528 us; speedup 1.0000x reference)
//
#include <hip/hip_runtime.h>

#define N_NODES   50000
#define IN_DIM    16
#define CONCAT    496
#define HID       512
#define OUT_DIM   64
#define RDIM      16
#define NEDGE     800000

// ---------------- init: h[:, 0:16] = feature, h[:, 16:496] = 0; zero stats ----------
__global__ __launch_bounds__(256) void k_init(const float* __restrict__ feat,
                                              float* __restrict__ h,
                                              float* __restrict__ stats) {
    long idx = (long)blockIdx.x * blockDim.x + threadIdx.x;
    if (idx < 1024) stats[idx] = 0.f;
    long total = (long)N_NODES * CONCAT;
    if (idx >= total) return;
    int n = (int)(idx / CONCAT);
    int c = (int)(idx % CONCAT);
    h[idx] = (c < IN_DIM) ? feat[n * IN_DIM + c] : 0.f;
}

// ---------------- scatter level: h[dst, OFF_OUT + t*D + d] += h[src, OFF_IN + d]*w ---
template<int D, int OFF_IN, int OFF_OUT>
__global__ __launch_bounds__(256) void k_scatter(const int* __restrict__ ei,
                                                 const float* __restrict__ ew,
                                                 const int* __restrict__ et,
                                                 float* h) {
    const int CH = D / 4;
    long idx = (long)blockIdx.x * blockDim.x + threadIdx.x;
    if (idx >= (long)NEDGE * CH) return;
    int e = (int)(idx / CH);
    int c = (int)(idx % CH) * 4;
    int src = ei[e];
    int dst = ei[NEDGE + e];
    float w  = ew[e];
    int  t   = et[e];
    const float4 v = *(const float4*)(h + (long)src * CONCAT + OFF_IN + c);
    float* o = h + (long)dst * CONCAT + OFF_OUT + t * D + c;
    atomicAdd(o + 0, v.x * w);
    atomicAdd(o + 1, v.y * w);
    atomicAdd(o + 2, v.z * w);
    atomicAdd(o + 3, v.w * w);
}

// ---------------- GEMM1: h1 = leaky_relu(h @ W1^T + b1); fused col sum/sumsq --------
__global__ __launch_bounds__(256) void k_gemm1(const float* __restrict__ h,
                                               const float* __restrict__ W1,
                                               const float* __restrict__ b1,
                                               float* __restrict__ h1,
                                               float* __restrict__ stats) {
    __shared__ float As[16][68];
    __shared__ float Bs[16][68];
    __shared__ float red[2][64][16];
    const int t  = threadIdx.x;
    const int tx = t & 15, ty = t >> 4;
    const int m0 = blockIdx.x * 64;
    const int j0 = blockIdx.y * 64;
    const int lm = t >> 2;          // 0..63
    const int lk = (t & 3) * 4;     // 0,4,8,12
    float acc[4][4] = {};

    for (int k0 = 0; k0 < CONCAT; k0 += 16) {
        int gm = m0 + lm;
        float4 av = (gm < N_NODES) ? *(const float4*)(h + (long)gm * CONCAT + k0 + lk)
                                   : make_float4(0.f, 0.f, 0.f, 0.f);
        As[lk + 0][lm] = av.x; As[lk + 1][lm] = av.y;
        As[lk + 2][lm] = av.z; As[lk + 3][lm] = av.w;
        float4 bv = *(const float4*)(W1 + (long)(j0 + lm) * CONCAT + k0 + lk);
        Bs[lk + 0][lm] = bv.x; Bs[lk + 1][lm] = bv.y;
        Bs[lk + 2][lm] = bv.z; Bs[lk + 3][lm] = bv.w;
        __syncthreads();
        #pragma unroll
        for (int kk = 0; kk < 16; ++kk) {
            float a[4], b[4];
            #pragma unroll
            for (int i = 0; i < 4; ++i) a[i] = As[kk][ty * 4 + i];
            #pragma unroll
            for (int j = 0; j < 4; ++j) b[j] = Bs[kk][tx * 4 + j];
            #pragma unroll
            for (int i = 0; i < 4; ++i)
                #pragma unroll
                for (int j = 0; j < 4; ++j)
                    acc[i][j] += a[i] * b[j];
        }
        __syncthreads();
    }

    float csum[4] = {0.f, 0.f, 0.f, 0.f};
    float csq[4]  = {0.f, 0.f, 0.f, 0.f};
    #pragma unroll
    for (int i = 0; i < 4; ++i) {
        int gm = m0 + ty * 4 + i;
        bool ok = gm < N_NODES;
        #pragma unroll
        for (int j = 0; j < 4; ++j) {
            int c = j0 + tx * 4 + j;
            float v = acc[i][j] + b1[c];
            v = v > 0.f ? v : 0.2f * v;
            if (ok) {
                h1[(long)gm * HID + c] = v;
                csum[j] += v;
                csq[j]  += v * v;
            }
        }
    }
    #pragma unroll
    for (int j = 0; j < 4; ++j) {
        red[0][tx * 4 + j][ty] = csum[j];
        red[1][tx * 4 + j][ty] = csq[j];
    }
    __syncthreads();
    if (t < 64) {
        float s = 0.f, q = 0.f;
        #pragma unroll
        for (int i = 0; i < 16; ++i) { s += red[0][t][i]; q += red[1][t][i]; }
        atomicAdd(&stats[j0 + t], s);
        atomicAdd(&stats[HID + j0 + t], q);
    }
}

// ---------------- fold BN into W2: W2t[k][j] = W2[j][k]*scale[k], b2f = b2 + W2@shift
__global__ __launch_bounds__(256) void k_fold(const float* __restrict__ stats,
                                              const float* __restrict__ gamma,
                                              const float* __restrict__ beta,
                                              const float* __restrict__ W2,
                                              const float* __restrict__ b2,
                                              float* __restrict__ W2t,
                                              float* __restrict__ b2f) {
    __shared__ float scale[HID], shift[HID];
    int t = threadIdx.x;
    for (int k = t; k < HID; k += 256) {
        float mu  = stats[k] * (1.f / N_NODES);
        float var = stats[HID + k] * (1.f / N_NODES) - mu * mu;
        var = fmaxf(var, 0.f);
        float sc = gamma[k] * rsqrtf(var + 1e-5f);
        scale[k] = sc;
        shift[k] = beta[k] - mu * sc;
    }
    __syncthreads();
    for (int idx = t; idx < HID * OUT_DIM; idx += 256) {
        int k = idx / OUT_DIM, j = idx % OUT_DIM;
        W2t[idx] = W2[j * HID + k] * scale[k];
    }
    if (t < OUT_DIM) {
        float s = b2[t];
        for (int k = 0; k < HID; ++k) s += W2[t * HID + k] * shift[k];
        b2f[t] = s;
    }
}

// ---------------- head: z = h1 @ W2t + b2f; out0 = z/||z||; out1 = z @ Wd^T + bd ----
__global__ __launch_bounds__(256) void k_head(const float* __restrict__ h1,
                                              const float* __restrict__ W2t,
                                              const float* __restrict__ b2f,
                                              const float* __restrict__ Wd,
                                              const float* __restrict__ bd,
                                              float* __restrict__ out) {
    __shared__ float As[16][68];
    __shared__ float Bs[16][68];
    __shared__ float zs[64][65];
    __shared__ float rnS[64];
    const int t  = threadIdx.x;
    const int tx = t & 15, ty = t >> 4;
    const int m0 = blockIdx.x * 64;
    const int lm = t >> 2;
    const int lk = (t & 3) * 4;
    float acc[4][4] = {};

    for (int k0 = 0; k0 < HID; k0 += 16) {
        int gm = m0 + lm;
        float4 av = (gm < N_NODES) ? *(const float4*)(h1 + (long)gm * HID + k0 + lk)
                                   : make_float4(0.f, 0.f, 0.f, 0.f);
        As[lk + 0][lm] = av.x; As[lk + 1][lm] = av.y;
        As[lk + 2][lm] = av.z; As[lk + 3][lm] = av.w;
        // B tile: W2t is [512][64] k-major
        int bk = t >> 4;           // 0..15
        int bj = (t & 15) * 4;     // 0..60
        float4 bv = *(const float4*)(W2t + (long)(k0 + bk) * OUT_DIM + bj);
        Bs[bk][bj + 0] = bv.x; Bs[bk][bj + 1] = bv.y;
        Bs[bk][bj + 2] = bv.z; Bs[bk][bj + 3] = bv.w;
        __syncthreads();
        #pragma unroll
        for (int kk = 0; kk < 16; ++kk) {
            float a[4], b[4];
            #pragma unroll
            for (int i = 0; i < 4; ++i) a[i] = As[kk][ty * 4 + i];
            #pragma unroll
            for (int j = 0; j < 4; ++j) b[j] = Bs[kk][tx * 4 + j];
            #pragma unroll
            for (int i = 0; i < 4; ++i)
                #pragma unroll
                for (int j = 0; j < 4; ++j)
                    acc[i][j] += a[i] * b[j];
        }
        __syncthreads();
    }

    // add bias, stash z tile
    #pragma unroll
    for (int i = 0; i < 4; ++i)
        #pragma unroll
        for (int j = 0; j < 4; ++j) {
            acc[i][j] += b2f[tx * 4 + j];
            zs[ty * 4 + i][tx * 4 + j] = acc[i][j];
        }
    __syncthreads();

    if (t < 64) {
        float ss = 0.f;
        #pragma unroll
        for (int j = 0; j < 64; ++j) { float v = zs[t][j]; ss += v * v; }
        rnS[t] = 1.f / fmaxf(sqrtf(ss), 1e-12f);
    }
    __syncthreads();

    // out0 = z / ||z||
    #pragma unroll
    for (int i = 0; i < 4; ++i) {
        int row = ty * 4 + i;
        int grow = m0 + row;
        if (grow < N_NODES) {
            float rn = rnS[row];
            float4 o = make_float4(acc[i][0] * rn, acc[i][1] * rn, acc[i][2] * rn, acc[i][3] * rn);
            *(float4*)(out + (long)grow * OUT_DIM + tx * 4) = o;
        }
    }

    // out1 = z @ Wd^T + bd   (1024 (row,i) pairs, 4 per thread)
    #pragma unroll
    for (int q = 0; q < 4; ++q) {
        int p = t * 4 + q;
        int row = p >> 4;
        int i = p & 15;
        int grow = m0 + row;
        if (grow < N_NODES) {
            float r = bd[i];
            const float* wd = Wd + i * OUT_DIM;
            #pragma unroll
            for (int j = 0; j < 64; ++j) r += zs[row][j] * wd[j];
            out[(long)N_NODES * OUT_DIM + (long)grow * RDIM + i] = r;
        }
    }
}

extern "C" void kernel_launch(void* const* d_in, const int* in_sizes, int n_in,
                              void* d_out, int out_size, void* d_ws, size_t ws_size,
                              hipStream_t stream) {
    const float* feat  = (const float*)d_in[0];
    const int*   ei    = (const int*)  d_in[1];
    const float* ew    = (const float*)d_in[2];
    const int*   et    = (const int*)  d_in[3];
    const float* W1    = (const float*)d_in[4];
    const float* b1    = (const float*)d_in[5];
    const float* gamma = (const float*)d_in[6];
    const float* beta  = (const float*)d_in[7];
    const float* W2    = (const float*)d_in[8];
    const float* b2    = (const float*)d_in[9];
    const float* Wd    = (const float*)d_in[10];
    const float* bd    = (const float*)d_in[11];
    float* out = (float*)d_out;

    float* ws    = (float*)d_ws;
    float* h     = ws;                       // N*496
    float* h1    = h  + (long)N_NODES * CONCAT;   // N*512
    float* stats = h1 + (long)N_NODES * HID;      // 1024
    float* W2t   = stats + 1024;                  // 512*64
    float* b2f   = W2t + HID * OUT_DIM;           // 64

    long initN = (long)N_NODES * CONCAT;
    k_init<<<(int)((initN + 255) / 256), 256, 0, stream>>>(feat, h, stats);

    k_scatter<16,   0,  16><<<(NEDGE * 4  + 255) / 256, 256, 0, stream>>>(ei, ew, et, h);
    k_scatter<32,  16,  48><<<(NEDGE * 8  + 255) / 256, 256, 0, stream>>>(ei, ew, et, h);
    k_scatter<64,  48, 112><<<(NEDGE * 16 + 255) / 256, 256, 0, stream>>>(ei, ew, et, h);
    k_scatter<128,112, 240><<<(NEDGE * 32 + 255) / 256, 256, 0, stream>>>(ei, ew, et, h);

    dim3 g1((N_NODES + 63) / 64, HID / 64);
    k_gemm1<<<g1, 256, 0, stream>>>(h, W1, b1, h1, stats);

    k_fold<<<1, 256, 0, stream>>>(stats, gamma, beta, W2, b2, W2t, b2f);

    k_head<<<(N_NODES + 63) / 64, 256, 0, stream>>>(h1, W2t, b2f, Wd, bd, out);
}

// Round 2
// 1087.268 us; speedup vs baseline: 2.8986x; 2.8986x over previous
//
#include <hip/hip_runtime.h>

#define N_NODES   50000
#define IN_DIM    16
#define CONCAT    496
#define HID       512
#define OUT_DIM   64
#define RDIM      16
#define NEDGE     800000

// ---- init: h[:, 0:16] = feature; zero stats + deg --------------------------------
__global__ __launch_bounds__(256) void k_init(const float* __restrict__ feat,
                                              float* __restrict__ h,
                                              float* __restrict__ stats,
                                              int* __restrict__ deg) {
    int idx = blockIdx.x * blockDim.x + threadIdx.x;
    if (idx < 1024) stats[idx] = 0.f;
    if (idx < N_NODES) deg[idx] = 0;
    if (idx >= N_NODES * IN_DIM) return;
    int n = idx / IN_DIM;
    int c = idx % IN_DIM;
    h[(long)n * CONCAT + c] = feat[idx];
}

// ---- CSR build -------------------------------------------------------------------
__global__ __launch_bounds__(256) void k_hist(const int* __restrict__ ei,
                                              int* __restrict__ deg) {
    int e = blockIdx.x * blockDim.x + threadIdx.x;
    if (e < NEDGE) atomicAdd(&deg[ei[NEDGE + e]], 1);
}

__global__ __launch_bounds__(1024) void k_scan(const int* __restrict__ deg,
                                               int* __restrict__ rowptr,
                                               int* __restrict__ cur) {
    __shared__ int part[1024];
    int t = threadIdx.x;
    const int CHUNK = (N_NODES + 1023) / 1024;  // 49
    int lo = t * CHUNK, hi = min(lo + CHUNK, N_NODES);
    int s = 0;
    for (int i = lo; i < hi; ++i) s += deg[i];
    part[t] = s;
    __syncthreads();
    for (int d = 1; d < 1024; d <<= 1) {
        int v = (t >= d) ? part[t - d] : 0;
        __syncthreads();
        part[t] += v;
        __syncthreads();
    }
    int base = (t > 0) ? part[t - 1] : 0;
    for (int i = lo; i < hi; ++i) {
        rowptr[i] = base;
        cur[i] = base;
        base += deg[i];
    }
    if (t == 1023) rowptr[N_NODES] = part[1023];
}

__global__ __launch_bounds__(256) void k_edges(const int* __restrict__ ei,
                                               const float* __restrict__ ew,
                                               const int* __restrict__ et,
                                               int* __restrict__ cur,
                                               int* __restrict__ srcs,
                                               float2* __restrict__ wp) {
    int e = blockIdx.x * blockDim.x + threadIdx.x;
    if (e >= NEDGE) return;
    int dst = ei[NEDGE + e];
    int pos = atomicAdd(&cur[dst], 1);
    srcs[pos] = ei[e];
    float w = ew[e];
    int ty = et[e];
    wp[pos] = make_float2(ty == 0 ? w : 0.f, ty == 1 ? w : 0.f);
}

// ---- gather-aggregate per level: G lanes per dst node, V floats per lane ---------
template<int D, int OFF_IN, int OFF_OUT, int G, int V>
__global__ __launch_bounds__(256) void k_gather(const int* __restrict__ rowptr,
                                                const int* __restrict__ srcs,
                                                const float2* __restrict__ wp,
                                                float* __restrict__ h) {
    const int NPB = 256 / G;
    int node = blockIdx.x * NPB + threadIdx.x / G;
    if (node >= N_NODES) return;
    int lane = threadIdx.x % G;
    int p0 = rowptr[node], p1 = rowptr[node + 1];
    float acc0[V] = {}, acc1[V] = {};
    const float* hin = h + OFF_IN + lane * V;
    for (int p = p0; p < p1; ++p) {
        int src = srcs[p];
        float2 w = wp[p];
        const float* row = hin + (long)src * CONCAT;
        #pragma unroll
        for (int v = 0; v < V; ++v) {
            float x = row[v];
            acc0[v] += x * w.x;
            acc1[v] += x * w.y;
        }
    }
    float* o = h + (long)node * CONCAT + OFF_OUT + lane * V;
    #pragma unroll
    for (int v = 0; v < V; ++v) { o[v] = acc0[v]; o[v + D] = acc1[v]; }
}

// ---- GEMM1: h1 = leaky_relu(h @ W1^T + b1); fused col sum/sumsq ------------------
__global__ __launch_bounds__(256) void k_gemm1(const float* __restrict__ h,
                                               const float* __restrict__ W1,
                                               const float* __restrict__ b1,
                                               float* __restrict__ h1,
                                               float* __restrict__ stats) {
    __shared__ float As[16][68];
    __shared__ float Bs[16][68];
    __shared__ float red[2][64][16];
    const int t  = threadIdx.x;
    const int tx = t & 15, ty = t >> 4;
    const int m0 = blockIdx.x * 64;
    const int j0 = blockIdx.y * 64;
    const int lm = t >> 2;          // 0..63
    const int lk = (t & 3) * 4;     // 0,4,8,12
    float acc[4][4] = {};

    for (int k0 = 0; k0 < CONCAT; k0 += 16) {
        int gm = m0 + lm;
        float4 av = (gm < N_NODES) ? *(const float4*)(h + (long)gm * CONCAT + k0 + lk)
                                   : make_float4(0.f, 0.f, 0.f, 0.f);
        As[lk + 0][lm] = av.x; As[lk + 1][lm] = av.y;
        As[lk + 2][lm] = av.z; As[lk + 3][lm] = av.w;
        float4 bv = *(const float4*)(W1 + (long)(j0 + lm) * CONCAT + k0 + lk);
        Bs[lk + 0][lm] = bv.x; Bs[lk + 1][lm] = bv.y;
        Bs[lk + 2][lm] = bv.z; Bs[lk + 3][lm] = bv.w;
        __syncthreads();
        #pragma unroll
        for (int kk = 0; kk < 16; ++kk) {
            float a[4], b[4];
            #pragma unroll
            for (int i = 0; i < 4; ++i) a[i] = As[kk][ty * 4 + i];
            #pragma unroll
            for (int j = 0; j < 4; ++j) b[j] = Bs[kk][tx * 4 + j];
            #pragma unroll
            for (int i = 0; i < 4; ++i)
                #pragma unroll
                for (int j = 0; j < 4; ++j)
                    acc[i][j] += a[i] * b[j];
        }
        __syncthreads();
    }

    float csum[4] = {0.f, 0.f, 0.f, 0.f};
    float csq[4]  = {0.f, 0.f, 0.f, 0.f};
    #pragma unroll
    for (int i = 0; i < 4; ++i) {
        int gm = m0 + ty * 4 + i;
        bool ok = gm < N_NODES;
        #pragma unroll
        for (int j = 0; j < 4; ++j) {
            int c = j0 + tx * 4 + j;
            float v = acc[i][j] + b1[c];
            v = v > 0.f ? v : 0.2f * v;
            if (ok) {
                h1[(long)gm * HID + c] = v;
                csum[j] += v;
                csq[j]  += v * v;
            }
        }
    }
    #pragma unroll
    for (int j = 0; j < 4; ++j) {
        red[0][tx * 4 + j][ty] = csum[j];
        red[1][tx * 4 + j][ty] = csq[j];
    }
    __syncthreads();
    if (t < 64) {
        float s = 0.f, q = 0.f;
        #pragma unroll
        for (int i = 0; i < 16; ++i) { s += red[0][t][i]; q += red[1][t][i]; }
        atomicAdd(&stats[j0 + t], s);
        atomicAdd(&stats[HID + j0 + t], q);
    }
}

// ---- fold BN into W2 -------------------------------------------------------------
__global__ __launch_bounds__(256) void k_fold(const float* __restrict__ stats,
                                              const float* __restrict__ gamma,
                                              const float* __restrict__ beta,
                                              const float* __restrict__ W2,
                                              const float* __restrict__ b2,
                                              float* __restrict__ W2t,
                                              float* __restrict__ b2f) {
    __shared__ float scale[HID], shift[HID];
    int t = threadIdx.x;
    for (int k = t; k < HID; k += 256) {
        float mu  = stats[k] * (1.f / N_NODES);
        float var = stats[HID + k] * (1.f / N_NODES) - mu * mu;
        var = fmaxf(var, 0.f);
        float sc = gamma[k] * rsqrtf(var + 1e-5f);
        scale[k] = sc;
        shift[k] = beta[k] - mu * sc;
    }
    __syncthreads();
    for (int idx = t; idx < HID * OUT_DIM; idx += 256) {
        int k = idx / OUT_DIM, j = idx % OUT_DIM;
        W2t[idx] = W2[j * HID + k] * scale[k];
    }
    if (t < OUT_DIM) {
        float s = b2[t];
        for (int k = 0; k < HID; ++k) s += W2[t * HID + k] * shift[k];
        b2f[t] = s;
    }
}

// ---- head: z = h1 @ W2t + b2f; out0 = z/||z||; out1 = z @ Wd^T + bd --------------
__global__ __launch_bounds__(256) void k_head(const float* __restrict__ h1,
                                              const float* __restrict__ W2t,
                                              const float* __restrict__ b2f,
                                              const float* __restrict__ Wd,
                                              const float* __restrict__ bd,
                                              float* __restrict__ out) {
    __shared__ float As[16][68];
    __shared__ float Bs[16][68];
    __shared__ float zs[64][65];
    __shared__ float rnS[64];
    const int t  = threadIdx.x;
    const int tx = t & 15, ty = t >> 4;
    const int m0 = blockIdx.x * 64;
    const int lm = t >> 2;
    const int lk = (t & 3) * 4;
    float acc[4][4] = {};

    for (int k0 = 0; k0 < HID; k0 += 16) {
        int gm = m0 + lm;
        float4 av = (gm < N_NODES) ? *(const float4*)(h1 + (long)gm * HID + k0 + lk)
                                   : make_float4(0.f, 0.f, 0.f, 0.f);
        As[lk + 0][lm] = av.x; As[lk + 1][lm] = av.y;
        As[lk + 2][lm] = av.z; As[lk + 3][lm] = av.w;
        int bk = t >> 4;
        int bj = (t & 15) * 4;
        float4 bv = *(const float4*)(W2t + (long)(k0 + bk) * OUT_DIM + bj);
        Bs[bk][bj + 0] = bv.x; Bs[bk][bj + 1] = bv.y;
        Bs[bk][bj + 2] = bv.z; Bs[bk][bj + 3] = bv.w;
        __syncthreads();
        #pragma unroll
        for (int kk = 0; kk < 16; ++kk) {
            float a[4], b[4];
            #pragma unroll
            for (int i = 0; i < 4; ++i) a[i] = As[kk][ty * 4 + i];
            #pragma unroll
            for (int j = 0; j < 4; ++j) b[j] = Bs[kk][tx * 4 + j];
            #pragma unroll
            for (int i = 0; i < 4; ++i)
                #pragma unroll
                for (int j = 0; j < 4; ++j)
                    acc[i][j] += a[i] * b[j];
        }
        __syncthreads();
    }

    #pragma unroll
    for (int i = 0; i < 4; ++i)
        #pragma unroll
        for (int j = 0; j < 4; ++j) {
            acc[i][j] += b2f[tx * 4 + j];
            zs[ty * 4 + i][tx * 4 + j] = acc[i][j];
        }
    __syncthreads();

    if (t < 64) {
        float ss = 0.f;
        #pragma unroll
        for (int j = 0; j < 64; ++j) { float v = zs[t][j]; ss += v * v; }
        rnS[t] = 1.f / fmaxf(sqrtf(ss), 1e-12f);
    }
    __syncthreads();

    #pragma unroll
    for (int i = 0; i < 4; ++i) {
        int row = ty * 4 + i;
        int grow = m0 + row;
        if (grow < N_NODES) {
            float rn = rnS[row];
            float4 o = make_float4(acc[i][0] * rn, acc[i][1] * rn, acc[i][2] * rn, acc[i][3] * rn);
            *(float4*)(out + (long)grow * OUT_DIM + tx * 4) = o;
        }
    }

    #pragma unroll
    for (int q = 0; q < 4; ++q) {
        int p = t * 4 + q;
        int row = p >> 4;
        int i = p & 15;
        int grow = m0 + row;
        if (grow < N_NODES) {
            float r = bd[i];
            const float* wd = Wd + i * OUT_DIM;
            #pragma unroll
            for (int j = 0; j < 64; ++j) r += zs[row][j] * wd[j];
            out[(long)N_NODES * OUT_DIM + (long)grow * RDIM + i] = r;
        }
    }
}

extern "C" void kernel_launch(void* const* d_in, const int* in_sizes, int n_in,
                              void* d_out, int out_size, void* d_ws, size_t ws_size,
                              hipStream_t stream) {
    const float* feat  = (const float*)d_in[0];
    const int*   ei    = (const int*)  d_in[1];
    const float* ew    = (const float*)d_in[2];
    const int*   et    = (const int*)  d_in[3];
    const float* W1    = (const float*)d_in[4];
    const float* b1    = (const float*)d_in[5];
    const float* gamma = (const float*)d_in[6];
    const float* beta  = (const float*)d_in[7];
    const float* W2    = (const float*)d_in[8];
    const float* b2    = (const float*)d_in[9];
    const float* Wd    = (const float*)d_in[10];
    const float* bd    = (const float*)d_in[11];
    float* out = (float*)d_out;

    float* ws    = (float*)d_ws;
    float* h     = ws;                            // N*496 f32
    float* h1    = h  + (long)N_NODES * CONCAT;   // N*512 f32
    float* stats = h1 + (long)N_NODES * HID;      // 1024
    float* W2t   = stats + 1024;                  // 512*64
    float* b2f   = W2t + HID * OUT_DIM;           // 64

    // CSR scratch aliased onto h1 (unused until k_gemm1, which only writes it)
    int*    deg    = (int*)h1;                    // 50000
    int*    rowptr = deg + 50008;                 // 50001
    int*    cur    = rowptr + 50008;              // 50000
    int*    srcs   = cur + 50008;                 // E
    float2* wp     = (float2*)(srcs + NEDGE);     // E float2 (8B-aligned: even offset)

    k_init<<<(N_NODES * IN_DIM + 255) / 256, 256, 0, stream>>>(feat, h, stats, deg);
    k_hist<<<(NEDGE + 255) / 256, 256, 0, stream>>>(ei, deg);
    k_scan<<<1, 1024, 0, stream>>>(deg, rowptr, cur);
    k_edges<<<(NEDGE + 255) / 256, 256, 0, stream>>>(ei, ew, et, cur, srcs, wp);

    k_gather<16,   0,  16, 16, 1><<<(N_NODES + 15) / 16, 256, 0, stream>>>(rowptr, srcs, wp, h);
    k_gather<32,  16,  48, 32, 1><<<(N_NODES + 7)  / 8,  256, 0, stream>>>(rowptr, srcs, wp, h);
    k_gather<64,  48, 112, 64, 1><<<(N_NODES + 3)  / 4,  256, 0, stream>>>(rowptr, srcs, wp, h);
    k_gather<128,112, 240, 64, 2><<<(N_NODES + 3)  / 4,  256, 0, stream>>>(rowptr, srcs, wp, h);

    dim3 g1((N_NODES + 63) / 64, HID / 64);
    k_gemm1<<<g1, 256, 0, stream>>>(h, W1, b1, h1, stats);

    k_fold<<<1, 256, 0, stream>>>(stats, gamma, beta, W2, b2, W2t, b2f);

    k_head<<<(N_NODES + 63) / 64, 256, 0, stream>>>(h1, W2t, b2f, Wd, bd, out);
}

// Round 3
// 748.253 us; speedup vs baseline: 4.2118x; 1.4531x over previous
//
#include <hip/hip_runtime.h>

#define N_NODES   50000
#define MP        50048          // rows padded to 128
#define IN_DIM    16
#define CONCAT    496
#define K2        512            // padded K for GEMM1
#define HID       512
#define OUT_DIM   64
#define RDIM      16
#define NEDGE     800000

typedef __attribute__((ext_vector_type(8))) short bf16x8;
typedef __attribute__((ext_vector_type(4))) float f32x4;

static __device__ __forceinline__ unsigned short f2bf(float x) {
    union { float f; unsigned u; } v; v.f = x;
    unsigned r = v.u + 0x7fff + ((v.u >> 16) & 1);
    return (unsigned short)(r >> 16);
}

#define GLDS16(gp, lp) \
    __builtin_amdgcn_global_load_lds((const __attribute__((address_space(1))) unsigned int*)(gp), \
                                     (__attribute__((address_space(3))) unsigned int*)(lp), 16, 0, 0)

// ---- init: feature -> h32[:,0:16] + hb[:,0:16]; zero pads/stats/deg --------------
__global__ __launch_bounds__(256) void k_init(const float* __restrict__ feat,
                                              float* __restrict__ h32,
                                              unsigned short* __restrict__ hb,
                                              float* __restrict__ stats,
                                              int* __restrict__ deg) {
    int idx = blockIdx.x * blockDim.x + threadIdx.x;
    if (idx < 1024) stats[idx] = 0.f;
    if (idx < N_NODES) deg[idx] = 0;
    if (idx < (MP - N_NODES) * K2) {               // zero padded rows of hb
        int r = N_NODES + (idx >> 9), c = idx & 511;
        hb[(long)r * K2 + c] = 0;
    }
    if (idx >= MP * IN_DIM) return;
    int n = idx >> 4, c = idx & 15;
    hb[(long)n * K2 + CONCAT + c] = 0;             // K pad cols 496..511
    if (n < N_NODES) {
        float x = feat[idx];
        h32[(long)n * 240 + c] = x;
        hb[(long)n * K2 + c] = f2bf(x);
    }
}

// ---- CSR build -------------------------------------------------------------------
__global__ __launch_bounds__(256) void k_hist(const int* __restrict__ ei,
                                              int* __restrict__ deg) {
    int e = blockIdx.x * blockDim.x + threadIdx.x;
    if (e < NEDGE) atomicAdd(&deg[ei[NEDGE + e]], 1);
}

__global__ __launch_bounds__(1024) void k_scan(const int* __restrict__ deg,
                                               int* __restrict__ rowptr,
                                               int* __restrict__ cur) {
    __shared__ int part[1024];
    int t = threadIdx.x;
    const int CHUNK = (N_NODES + 1023) / 1024;
    int lo = t * CHUNK, hi = min(lo + CHUNK, N_NODES);
    int s = 0;
    for (int i = lo; i < hi; ++i) s += deg[i];
    part[t] = s;
    __syncthreads();
    for (int d = 1; d < 1024; d <<= 1) {
        int v = (t >= d) ? part[t - d] : 0;
        __syncthreads();
        part[t] += v;
        __syncthreads();
    }
    int base = (t > 0) ? part[t - 1] : 0;
    for (int i = lo; i < hi; ++i) {
        rowptr[i] = base;
        cur[i] = base;
        base += deg[i];
    }
    if (t == 1023) rowptr[N_NODES] = part[1023];
}

__global__ __launch_bounds__(256) void k_edges(const int* __restrict__ ei,
                                               const float* __restrict__ ew,
                                               const int* __restrict__ et,
                                               int* __restrict__ cur,
                                               int* __restrict__ srcs,
                                               float2* __restrict__ wp) {
    int e = blockIdx.x * blockDim.x + threadIdx.x;
    if (e >= NEDGE) return;
    int dst = ei[NEDGE + e];
    int pos = atomicAdd(&cur[dst], 1);
    srcs[pos] = ei[e];
    float w = ew[e];
    int ty = et[e];
    wp[pos] = make_float2(ty == 0 ? w : 0.f, ty == 1 ? w : 0.f);
}

// ---- W1 -> bf16, K-padded, aliased over dead h32 ---------------------------------
__global__ __launch_bounds__(256) void k_cvtw(const float* __restrict__ W1,
                                              unsigned short* __restrict__ W1b) {
    int idx = blockIdx.x * blockDim.x + threadIdx.x;
    if (idx >= HID * K2) return;
    int n = idx >> 9, k = idx & 511;
    W1b[idx] = (k < CONCAT) ? f2bf(W1[n * CONCAT + k]) : (unsigned short)0;
}

// ---- gather-aggregate: G lanes per dst, V floats per lane; unroll-2 --------------
template<int D, int OFF_IN, int OFF32, int OFFB, int G, int V, bool W32>
__global__ __launch_bounds__(256) void k_gather(const int* __restrict__ rowptr,
                                                const int* __restrict__ srcs,
                                                const float2* __restrict__ wp,
                                                float* __restrict__ h32,
                                                unsigned short* __restrict__ hb) {
    const int NPB = 256 / G;
    int node = blockIdx.x * NPB + threadIdx.x / G;
    if (node >= N_NODES) return;
    int lane = threadIdx.x % G;
    int p0 = rowptr[node], p1 = rowptr[node + 1];
    float a0[V] = {}, a1[V] = {}, c0[V] = {}, c1[V] = {};
    const float* hin = h32 + OFF_IN + lane * V;
    int p = p0;
    for (; p + 2 <= p1; p += 2) {
        int s0 = srcs[p], s1 = srcs[p + 1];
        float2 w0 = wp[p], w1 = wp[p + 1];
        const float* r0 = hin + (long)s0 * 240;
        const float* r1 = hin + (long)s1 * 240;
        #pragma unroll
        for (int v = 0; v < V; ++v) {
            float x0 = r0[v], x1 = r1[v];
            a0[v] += x0 * w0.x; a1[v] += x0 * w0.y;
            c0[v] += x1 * w1.x; c1[v] += x1 * w1.y;
        }
    }
    if (p < p1) {
        int s0 = srcs[p];
        float2 w0 = wp[p];
        const float* r0 = hin + (long)s0 * 240;
        #pragma unroll
        for (int v = 0; v < V; ++v) {
            float x0 = r0[v];
            a0[v] += x0 * w0.x; a1[v] += x0 * w0.y;
        }
    }
    #pragma unroll
    for (int v = 0; v < V; ++v) { a0[v] += c0[v]; a1[v] += c1[v]; }

    if (W32) {
        float* o = h32 + (long)node * 240 + OFF32 + lane * V;
        #pragma unroll
        for (int v = 0; v < V; ++v) { o[v] = a0[v]; o[v + D] = a1[v]; }
    }
    unsigned short* ob = hb + (long)node * K2 + OFFB + lane * V;
    #pragma unroll
    for (int v = 0; v < V; ++v) { ob[v] = f2bf(a0[v]); ob[v + D] = f2bf(a1[v]); }
}

// ---- GEMM1 via MFMA: h1 = leaky_relu(hb @ W1b^T + b1), fused col stats -----------
// 128x128 tile, BK=64, 4 waves (2x2 of 64x64), LDS XOR-swizzled (chunk ^= row&7)
__global__ __launch_bounds__(256) void k_gemm1_mfma(const unsigned short* __restrict__ hb,
                                                    const unsigned short* __restrict__ W1b,
                                                    const float* __restrict__ b1,
                                                    float* __restrict__ h1,
                                                    float* __restrict__ stats) {
    __shared__ unsigned short Al[128 * 64];
    __shared__ unsigned short Bl[128 * 64];
    const int t = threadIdx.x;
    const int lane = t & 63;
    const int w = t >> 6;
    const int wr = w >> 1, wc = w & 1;
    const int m0 = blockIdx.x * 128;
    const int n0 = blockIdx.y * 128;

    f32x4 acc[4][4] = {};

    for (int kt = 0; kt < K2 / 64; ++kt) {
        const int kbase = kt * 64;
        #pragma unroll
        for (int i = 0; i < 4; ++i) {
            int tt = i * 256 + t;
            int r = tt >> 3;                    // tile row 0..127
            int s = tt & 7;                     // stored 16B chunk
            int c = s ^ (r & 7);                // data chunk (inverse-swizzled source)
            const unsigned short* ga = hb  + (long)(m0 + r) * K2 + kbase + c * 8;
            GLDS16(ga, Al + tt * 8);
            const unsigned short* gb = W1b + (long)(n0 + r) * K2 + kbase + c * 8;
            GLDS16(gb, Bl + tt * 8);
        }
        asm volatile("s_waitcnt vmcnt(0)" ::: "memory");
        __syncthreads();
        #pragma unroll
        for (int ks = 0; ks < 2; ++ks) {
            bf16x8 af[4], bfr[4];
            #pragma unroll
            for (int mi = 0; mi < 4; ++mi) {
                int R = wr * 64 + mi * 16 + (lane & 15);
                int sc = (ks * 4 + (lane >> 4)) ^ (R & 7);
                af[mi] = *(const bf16x8*)(Al + R * 64 + sc * 8);
            }
            #pragma unroll
            for (int nj = 0; nj < 4; ++nj) {
                int R = wc * 64 + nj * 16 + (lane & 15);
                int sc = (ks * 4 + (lane >> 4)) ^ (R & 7);
                bfr[nj] = *(const bf16x8*)(Bl + R * 64 + sc * 8);
            }
            #pragma unroll
            for (int mi = 0; mi < 4; ++mi)
                #pragma unroll
                for (int nj = 0; nj < 4; ++nj)
                    acc[mi][nj] = __builtin_amdgcn_mfma_f32_16x16x32_bf16(
                        af[mi], bfr[nj], acc[mi][nj], 0, 0, 0);
        }
        __syncthreads();
    }

    // epilogue: bias + leaky_relu, store f32 h1, fused column sum/sumsq
    const int cb = n0 + wc * 64;
    const bool fullblk = (m0 + 128 <= N_NODES);
    float csum[4] = {0.f, 0.f, 0.f, 0.f};
    float csq[4]  = {0.f, 0.f, 0.f, 0.f};
    #pragma unroll
    for (int mi = 0; mi < 4; ++mi) {
        int rbase = m0 + wr * 64 + mi * 16 + (lane >> 4) * 4;
        #pragma unroll
        for (int nj = 0; nj < 4; ++nj) {
            int col = cb + nj * 16 + (lane & 15);
            float bias = b1[col];
            #pragma unroll
            for (int r = 0; r < 4; ++r) {
                int row = rbase + r;
                float v = acc[mi][nj][r] + bias;
                v = v > 0.f ? v : 0.2f * v;
                if (fullblk || row < N_NODES) {
                    h1[(long)row * HID + col] = v;
                    csum[nj] += v;
                    csq[nj]  += v * v;
                }
            }
        }
    }
    #pragma unroll
    for (int nj = 0; nj < 4; ++nj) {
        float s = csum[nj], q = csq[nj];
        s += __shfl_xor(s, 16); q += __shfl_xor(q, 16);
        s += __shfl_xor(s, 32); q += __shfl_xor(q, 32);
        if (lane < 16) {
            int col = cb + nj * 16 + lane;
            atomicAdd(&stats[col], s);
            atomicAdd(&stats[HID + col], q);
        }
    }
}

// ---- fold BN into W2 -------------------------------------------------------------
__global__ __launch_bounds__(256) void k_fold(const float* __restrict__ stats,
                                              const float* __restrict__ gamma,
                                              const float* __restrict__ beta,
                                              const float* __restrict__ W2,
                                              const float* __restrict__ b2,
                                              float* __restrict__ W2t,
                                              float* __restrict__ b2f) {
    __shared__ float scale[HID], shift[HID];
    int t = threadIdx.x;
    for (int k = t; k < HID; k += 256) {
        float mu  = stats[k] * (1.f / N_NODES);
        float var = stats[HID + k] * (1.f / N_NODES) - mu * mu;
        var = fmaxf(var, 0.f);
        float sc = gamma[k] * rsqrtf(var + 1e-5f);
        scale[k] = sc;
        shift[k] = beta[k] - mu * sc;
    }
    __syncthreads();
    for (int idx = t; idx < HID * OUT_DIM; idx += 256) {
        int k = idx / OUT_DIM, j = idx % OUT_DIM;
        W2t[idx] = W2[j * HID + k] * scale[k];
    }
    if (t < OUT_DIM) {
        float s = b2[t];
        for (int k = 0; k < HID; ++k) s += W2[t * HID + k] * shift[k];
        b2f[t] = s;
    }
}

// ---- head: z = h1 @ W2t + b2f; out0 = z/||z||; out1 = z @ Wd^T + bd --------------
__global__ __launch_bounds__(256) void k_head(const float* __restrict__ h1,
                                              const float* __restrict__ W2t,
                                              const float* __restrict__ b2f,
                                              const float* __restrict__ Wd,
                                              const float* __restrict__ bd,
                                              float* __restrict__ out) {
    __shared__ float As[16][68];
    __shared__ float Bs[16][68];
    __shared__ float zs[64][65];
    __shared__ float rnS[64];
    const int t  = threadIdx.x;
    const int tx = t & 15, ty = t >> 4;
    const int m0 = blockIdx.x * 64;
    const int lm = t >> 2;
    const int lk = (t & 3) * 4;
    float acc[4][4] = {};

    for (int k0 = 0; k0 < HID; k0 += 16) {
        int gm = m0 + lm;
        float4 av = (gm < N_NODES) ? *(const float4*)(h1 + (long)gm * HID + k0 + lk)
                                   : make_float4(0.f, 0.f, 0.f, 0.f);
        As[lk + 0][lm] = av.x; As[lk + 1][lm] = av.y;
        As[lk + 2][lm] = av.z; As[lk + 3][lm] = av.w;
        int bk = t >> 4;
        int bj = (t & 15) * 4;
        float4 bv = *(const float4*)(W2t + (long)(k0 + bk) * OUT_DIM + bj);
        Bs[bk][bj + 0] = bv.x; Bs[bk][bj + 1] = bv.y;
        Bs[bk][bj + 2] = bv.z; Bs[bk][bj + 3] = bv.w;
        __syncthreads();
        #pragma unroll
        for (int kk = 0; kk < 16; ++kk) {
            float a[4], b[4];
            #pragma unroll
            for (int i = 0; i < 4; ++i) a[i] = As[kk][ty * 4 + i];
            #pragma unroll
            for (int j = 0; j < 4; ++j) b[j] = Bs[kk][tx * 4 + j];
            #pragma unroll
            for (int i = 0; i < 4; ++i)
                #pragma unroll
                for (int j = 0; j < 4; ++j)
                    acc[i][j] += a[i] * b[j];
        }
        __syncthreads();
    }

    #pragma unroll
    for (int i = 0; i < 4; ++i)
        #pragma unroll
        for (int j = 0; j < 4; ++j) {
            acc[i][j] += b2f[tx * 4 + j];
            zs[ty * 4 + i][tx * 4 + j] = acc[i][j];
        }
    __syncthreads();

    if (t < 64) {
        float ss = 0.f;
        #pragma unroll
        for (int j = 0; j < 64; ++j) { float v = zs[t][j]; ss += v * v; }
        rnS[t] = 1.f / fmaxf(sqrtf(ss), 1e-12f);
    }
    __syncthreads();

    #pragma unroll
    for (int i = 0; i < 4; ++i) {
        int row = ty * 4 + i;
        int grow = m0 + row;
        if (grow < N_NODES) {
            float rn = rnS[row];
            float4 o = make_float4(acc[i][0] * rn, acc[i][1] * rn, acc[i][2] * rn, acc[i][3] * rn);
            *(float4*)(out + (long)grow * OUT_DIM + tx * 4) = o;
        }
    }

    #pragma unroll
    for (int q = 0; q < 4; ++q) {
        int p = t * 4 + q;
        int row = p >> 4;
        int i = p & 15;
        int grow = m0 + row;
        if (grow < N_NODES) {
            float r = bd[i];
            const float* wd = Wd + i * OUT_DIM;
            #pragma unroll
            for (int j = 0; j < 64; ++j) r += zs[row][j] * wd[j];
            out[(long)N_NODES * OUT_DIM + (long)grow * RDIM + i] = r;
        }
    }
}

extern "C" void kernel_launch(void* const* d_in, const int* in_sizes, int n_in,
                              void* d_out, int out_size, void* d_ws, size_t ws_size,
                              hipStream_t stream) {
    const float* feat  = (const float*)d_in[0];
    const int*   ei    = (const int*)  d_in[1];
    const float* ew    = (const float*)d_in[2];
    const int*   et    = (const int*)  d_in[3];
    const float* W1    = (const float*)d_in[4];
    const float* b1    = (const float*)d_in[5];
    const float* gamma = (const float*)d_in[6];
    const float* beta  = (const float*)d_in[7];
    const float* W2    = (const float*)d_in[8];
    const float* b2    = (const float*)d_in[9];
    const float* Wd    = (const float*)d_in[10];
    const float* bd    = (const float*)d_in[11];
    float* out = (float*)d_out;

    float* ws = (float*)d_ws;
    float*          h32   = ws;                                  // [N][240] f32 (dead after L4 gather)
    unsigned short* hb    = (unsigned short*)(ws + 12000000);    // [MP][512] bf16
    float*          h1    = ws + 12000000 + 12812288;            // [N][512] f32
    float*          stats = h1 + (long)N_NODES * HID;            // 1024
    float*          W2t   = stats + 1024;                        // 512*64
    float*          b2f   = W2t + HID * OUT_DIM;                 // 64
    unsigned short* W1b   = (unsigned short*)h32;                // aliased (used after gathers)

    // CSR scratch aliased onto h1 (dead once gathers finish; gemm1 only writes h1)
    int*    deg    = (int*)h1;
    int*    rowptr = deg + 50008;
    int*    cur    = rowptr + 50008;
    int*    srcs   = cur + 50008;
    float2* wp     = (float2*)(srcs + NEDGE);

    k_init<<<(MP * IN_DIM + 255) / 256, 256, 0, stream>>>(feat, h32, hb, stats, deg);
    k_hist<<<(NEDGE + 255) / 256, 256, 0, stream>>>(ei, deg);
    k_scan<<<1, 1024, 0, stream>>>(deg, rowptr, cur);
    k_edges<<<(NEDGE + 255) / 256, 256, 0, stream>>>(ei, ew, et, cur, srcs, wp);

    k_gather<16,   0,  16,  16, 16, 1, true ><<<(N_NODES + 15) / 16, 256, 0, stream>>>(rowptr, srcs, wp, h32, hb);
    k_gather<32,  16,  48,  48, 32, 1, true ><<<(N_NODES + 7)  / 8,  256, 0, stream>>>(rowptr, srcs, wp, h32, hb);
    k_gather<64,  48, 112, 112, 64, 1, true ><<<(N_NODES + 3)  / 4,  256, 0, stream>>>(rowptr, srcs, wp, h32, hb);
    k_gather<128,112,   0, 240, 64, 2, false><<<(N_NODES + 3)  / 4,  256, 0, stream>>>(rowptr, srcs, wp, h32, hb);

    k_cvtw<<<(HID * K2 + 255) / 256, 256, 0, stream>>>(W1, W1b);

    dim3 g1(MP / 128, K2 / 128);   // (391, 4)
    k_gemm1_mfma<<<g1, 256, 0, stream>>>(hb, W1b, b1, h1, stats);

    k_fold<<<1, 256, 0, stream>>>(stats, gamma, beta, W2, b2, W2t, b2f);

    k_head<<<(N_NODES + 63) / 64, 256, 0, stream>>>(h1, W2t, b2f, Wd, bd, out);
}

// Round 4
// 606.846 us; speedup vs baseline: 5.1933x; 1.2330x over previous
//
#include <hip/hip_runtime.h>

#define N_NODES   50000
#define MP        50048          // rows padded to 128
#define IN_DIM    16
#define CONCAT    496
#define K2        512            // padded K for GEMM1
#define HID       512
#define OUT_DIM   64
#define RDIM      16
#define NEDGE     800000

typedef __attribute__((ext_vector_type(8))) short bf16x8;
typedef __attribute__((ext_vector_type(4))) float f32x4;

static __device__ __forceinline__ unsigned short f2bf(float x) {
    union { float f; unsigned u; } v; v.f = x;
    unsigned r = v.u + 0x7fff + ((v.u >> 16) & 1);
    return (unsigned short)(r >> 16);
}

#define GLDS16(gp, lp) \
    __builtin_amdgcn_global_load_lds((const __attribute__((address_space(1))) unsigned int*)(gp), \
                                     (__attribute__((address_space(3))) unsigned int*)(lp), 16, 0, 0)

// ---- init: feature -> h32[:,0:16] + hb[:,0:16]; zero pads/stats/deg --------------
__global__ __launch_bounds__(256) void k_init(const float* __restrict__ feat,
                                              float* __restrict__ h32,
                                              unsigned short* __restrict__ hb,
                                              float* __restrict__ stats,
                                              int* __restrict__ deg) {
    int idx = blockIdx.x * blockDim.x + threadIdx.x;
    if (idx < 1024) stats[idx] = 0.f;
    if (idx < N_NODES) deg[idx] = 0;
    if (idx < (MP - N_NODES) * K2) {               // zero padded rows of hb
        int r = N_NODES + (idx >> 9), c = idx & 511;
        hb[(long)r * K2 + c] = 0;
    }
    if (idx >= MP * IN_DIM) return;
    int n = idx >> 4, c = idx & 15;
    hb[(long)n * K2 + CONCAT + c] = 0;             // K pad cols 496..511
    if (n < N_NODES) {
        float x = feat[idx];
        h32[(long)n * 240 + c] = x;
        hb[(long)n * K2 + c] = f2bf(x);
    }
}

// ---- CSR build -------------------------------------------------------------------
__global__ __launch_bounds__(256) void k_hist(const int* __restrict__ ei,
                                              int* __restrict__ deg) {
    int e = blockIdx.x * blockDim.x + threadIdx.x;
    if (e < NEDGE) atomicAdd(&deg[ei[NEDGE + e]], 1);
}

__global__ __launch_bounds__(1024) void k_scan(const int* __restrict__ deg,
                                               int* __restrict__ rowptr,
                                               int* __restrict__ cur) {
    __shared__ int part[1024];
    int t = threadIdx.x;
    const int CHUNK = (N_NODES + 1023) / 1024;
    int lo = t * CHUNK, hi = min(lo + CHUNK, N_NODES);
    int s = 0;
    for (int i = lo; i < hi; ++i) s += deg[i];
    part[t] = s;
    __syncthreads();
    for (int d = 1; d < 1024; d <<= 1) {
        int v = (t >= d) ? part[t - d] : 0;
        __syncthreads();
        part[t] += v;
        __syncthreads();
    }
    int base = (t > 0) ? part[t - 1] : 0;
    for (int i = lo; i < hi; ++i) {
        rowptr[i] = base;
        cur[i] = base;
        base += deg[i];
    }
    if (t == 1023) rowptr[N_NODES] = part[1023];
}

__global__ __launch_bounds__(256) void k_edges(const int* __restrict__ ei,
                                               const float* __restrict__ ew,
                                               const int* __restrict__ et,
                                               int* __restrict__ cur,
                                               int* __restrict__ srcs,
                                               float2* __restrict__ wp) {
    int e = blockIdx.x * blockDim.x + threadIdx.x;
    if (e >= NEDGE) return;
    int dst = ei[NEDGE + e];
    int pos = atomicAdd(&cur[dst], 1);
    srcs[pos] = ei[e];
    float w = ew[e];
    int ty = et[e];
    wp[pos] = make_float2(ty == 0 ? w : 0.f, ty == 1 ? w : 0.f);
}

// ---- W1 -> bf16, K-padded, aliased over dead h32 ---------------------------------
__global__ __launch_bounds__(256) void k_cvtw(const float* __restrict__ W1,
                                              unsigned short* __restrict__ W1b) {
    int idx = blockIdx.x * blockDim.x + threadIdx.x;
    if (idx >= HID * K2) return;
    int n = idx >> 9, k = idx & 511;
    W1b[idx] = (k < CONCAT) ? f2bf(W1[n * CONCAT + k]) : (unsigned short)0;
}

// ---- gather-aggregate: G lanes per dst, V floats per lane; unroll-2 --------------
template<int D, int OFF_IN, int OFF32, int OFFB, int G, int V, bool W32>
__global__ __launch_bounds__(256) void k_gather(const int* __restrict__ rowptr,
                                                const int* __restrict__ srcs,
                                                const float2* __restrict__ wp,
                                                float* __restrict__ h32,
                                                unsigned short* __restrict__ hb) {
    const int NPB = 256 / G;
    int node = blockIdx.x * NPB + threadIdx.x / G;
    if (node >= N_NODES) return;
    int lane = threadIdx.x % G;
    int p0 = rowptr[node], p1 = rowptr[node + 1];
    float a0[V] = {}, a1[V] = {}, c0[V] = {}, c1[V] = {};
    const float* hin = h32 + OFF_IN + lane * V;
    int p = p0;
    for (; p + 2 <= p1; p += 2) {
        int s0 = srcs[p], s1 = srcs[p + 1];
        float2 w0 = wp[p], w1 = wp[p + 1];
        const float* r0 = hin + (long)s0 * 240;
        const float* r1 = hin + (long)s1 * 240;
        #pragma unroll
        for (int v = 0; v < V; ++v) {
            float x0 = r0[v], x1 = r1[v];
            a0[v] += x0 * w0.x; a1[v] += x0 * w0.y;
            c0[v] += x1 * w1.x; c1[v] += x1 * w1.y;
        }
    }
    if (p < p1) {
        int s0 = srcs[p];
        float2 w0 = wp[p];
        const float* r0 = hin + (long)s0 * 240;
        #pragma unroll
        for (int v = 0; v < V; ++v) {
            float x0 = r0[v];
            a0[v] += x0 * w0.x; a1[v] += x0 * w0.y;
        }
    }
    #pragma unroll
    for (int v = 0; v < V; ++v) { a0[v] += c0[v]; a1[v] += c1[v]; }

    if (W32) {
        float* o = h32 + (long)node * 240 + OFF32 + lane * V;
        #pragma unroll
        for (int v = 0; v < V; ++v) { o[v] = a0[v]; o[v + D] = a1[v]; }
    }
    unsigned short* ob = hb + (long)node * K2 + OFFB + lane * V;
    #pragma unroll
    for (int v = 0; v < V; ++v) { ob[v] = f2bf(a0[v]); ob[v + D] = f2bf(a1[v]); }
}

// ---- GEMM1 via MFMA: h1b = bf16(leaky_relu(hb @ W1b^T + b1)), fused col stats ----
__global__ __launch_bounds__(256) void k_gemm1_mfma(const unsigned short* __restrict__ hb,
                                                    const unsigned short* __restrict__ W1b,
                                                    const float* __restrict__ b1,
                                                    unsigned short* __restrict__ h1b,
                                                    float* __restrict__ stats) {
    __shared__ unsigned short Al[128 * 64];
    __shared__ unsigned short Bl[128 * 64];
    const int t = threadIdx.x;
    const int lane = t & 63;
    const int w = t >> 6;
    const int wr = w >> 1, wc = w & 1;
    const int m0 = blockIdx.x * 128;
    const int n0 = blockIdx.y * 128;

    f32x4 acc[4][4] = {};

    for (int kt = 0; kt < K2 / 64; ++kt) {
        const int kbase = kt * 64;
        #pragma unroll
        for (int i = 0; i < 4; ++i) {
            int tt = i * 256 + t;
            int r = tt >> 3;
            int s = tt & 7;
            int c = s ^ (r & 7);
            GLDS16(hb  + (long)(m0 + r) * K2 + kbase + c * 8, Al + tt * 8);
            GLDS16(W1b + (long)(n0 + r) * K2 + kbase + c * 8, Bl + tt * 8);
        }
        asm volatile("s_waitcnt vmcnt(0)" ::: "memory");
        __syncthreads();
        #pragma unroll
        for (int ks = 0; ks < 2; ++ks) {
            bf16x8 af[4], bfr[4];
            #pragma unroll
            for (int mi = 0; mi < 4; ++mi) {
                int R = wr * 64 + mi * 16 + (lane & 15);
                int sc = (ks * 4 + (lane >> 4)) ^ (R & 7);
                af[mi] = *(const bf16x8*)(Al + R * 64 + sc * 8);
            }
            #pragma unroll
            for (int nj = 0; nj < 4; ++nj) {
                int R = wc * 64 + nj * 16 + (lane & 15);
                int sc = (ks * 4 + (lane >> 4)) ^ (R & 7);
                bfr[nj] = *(const bf16x8*)(Bl + R * 64 + sc * 8);
            }
            #pragma unroll
            for (int mi = 0; mi < 4; ++mi)
                #pragma unroll
                for (int nj = 0; nj < 4; ++nj)
                    acc[mi][nj] = __builtin_amdgcn_mfma_f32_16x16x32_bf16(
                        af[mi], bfr[nj], acc[mi][nj], 0, 0, 0);
        }
        __syncthreads();
    }

    const int cb = n0 + wc * 64;
    float csum[4] = {0.f, 0.f, 0.f, 0.f};
    float csq[4]  = {0.f, 0.f, 0.f, 0.f};
    #pragma unroll
    for (int mi = 0; mi < 4; ++mi) {
        int rbase = m0 + wr * 64 + mi * 16 + (lane >> 4) * 4;
        #pragma unroll
        for (int nj = 0; nj < 4; ++nj) {
            int col = cb + nj * 16 + (lane & 15);
            float bias = b1[col];
            #pragma unroll
            for (int r = 0; r < 4; ++r) {
                int row = rbase + r;
                float v = acc[mi][nj][r] + bias;
                v = v > 0.f ? v : 0.2f * v;
                h1b[(long)row * HID + col] = f2bf(v);   // all MP rows (pad rows finite)
                if (row < N_NODES) {
                    csum[nj] += v;
                    csq[nj]  += v * v;
                }
            }
        }
    }
    #pragma unroll
    for (int nj = 0; nj < 4; ++nj) {
        float s = csum[nj], q = csq[nj];
        s += __shfl_xor(s, 16); q += __shfl_xor(q, 16);
        s += __shfl_xor(s, 32); q += __shfl_xor(q, 32);
        if (lane < 16) {
            int col = cb + nj * 16 + lane;
            atomicAdd(&stats[col], s);
            atomicAdd(&stats[HID + col], q);
        }
    }
}

// ---- fold BN into W2: W2b[j][k] = bf16(W2[j][k]*scale[k]); b2f = b2 + W2@shift ---
__global__ __launch_bounds__(256) void k_fold(const float* __restrict__ stats,
                                              const float* __restrict__ gamma,
                                              const float* __restrict__ beta,
                                              const float* __restrict__ W2,
                                              const float* __restrict__ b2,
                                              unsigned short* __restrict__ W2b,
                                              float* __restrict__ b2f) {
    __shared__ float scale[HID], shift[HID];
    int t = threadIdx.x;
    for (int k = t; k < HID; k += 256) {
        float mu  = stats[k] * (1.f / N_NODES);
        float var = stats[HID + k] * (1.f / N_NODES) - mu * mu;
        var = fmaxf(var, 0.f);
        float sc = gamma[k] * rsqrtf(var + 1e-5f);
        scale[k] = sc;
        shift[k] = beta[k] - mu * sc;
    }
    __syncthreads();
    for (int idx = t; idx < OUT_DIM * HID; idx += 256) {
        int k = idx & 511;
        W2b[idx] = f2bf(W2[idx] * scale[k]);
    }
    if (t < OUT_DIM) {
        float s = b2[t];
        for (int k = 0; k < HID; ++k) s += W2[t * HID + k] * shift[k];
        b2f[t] = s;
    }
}

// ---- head via MFMA: z = h1b @ W2b^T + b2f; out0 = z/||z||; out1 = z @ Wd^T + bd --
// 128-row tile, 4 waves (32 rows each), BK=64, XOR-swizzled LDS
__global__ __launch_bounds__(256) void k_head_mfma(const unsigned short* __restrict__ h1b,
                                                   const unsigned short* __restrict__ W2b,
                                                   const float* __restrict__ b2f,
                                                   const float* __restrict__ Wd,
                                                   const float* __restrict__ bd,
                                                   float* __restrict__ out) {
    __shared__ unsigned short Al[128 * 64];   // A tile; reused as z_lds in epilogue
    __shared__ unsigned short Bl[64 * 64];
    __shared__ unsigned short WdL[16 * 64];
    const int t = threadIdx.x;
    const int lane = t & 63;
    const int w = t >> 6;
    const int l15 = lane & 15, hi = lane >> 4;
    const int m0 = blockIdx.x * 128;

    // stage Wd once (f32 -> bf16, swizzled into B-frag layout)
    for (int i = t; i < 16 * 64; i += 256) {
        int r = i >> 6, c = i & 63;
        WdL[r * 64 + (((c >> 3) ^ (r & 7)) << 3) + (c & 7)] = f2bf(Wd[i]);
    }

    f32x4 acc[2][4] = {};

    for (int kt = 0; kt < 8; ++kt) {
        const int kbase = kt * 64;
        #pragma unroll
        for (int i = 0; i < 4; ++i) {                 // A: 1024 chunks
            int tt = i * 256 + t;
            int r = tt >> 3, s = tt & 7, c = s ^ (r & 7);
            GLDS16(h1b + (long)(m0 + r) * HID + kbase + c * 8, Al + tt * 8);
        }
        #pragma unroll
        for (int i = 0; i < 2; ++i) {                 // B: 512 chunks
            int tt = i * 256 + t;
            int r = tt >> 3, s = tt & 7, c = s ^ (r & 7);
            GLDS16(W2b + (long)r * HID + kbase + c * 8, Bl + tt * 8);
        }
        asm volatile("s_waitcnt vmcnt(0)" ::: "memory");
        __syncthreads();
        #pragma unroll
        for (int ks = 0; ks < 2; ++ks) {
            bf16x8 af[2], bfr[4];
            #pragma unroll
            for (int mi = 0; mi < 2; ++mi) {
                int R = w * 32 + mi * 16 + l15;
                int sc = (ks * 4 + hi) ^ (R & 7);
                af[mi] = *(const bf16x8*)(Al + R * 64 + sc * 8);
            }
            #pragma unroll
            for (int nj = 0; nj < 4; ++nj) {
                int R = nj * 16 + l15;
                int sc = (ks * 4 + hi) ^ (R & 7);
                bfr[nj] = *(const bf16x8*)(Bl + R * 64 + sc * 8);
            }
            #pragma unroll
            for (int mi = 0; mi < 2; ++mi)
                #pragma unroll
                for (int nj = 0; nj < 4; ++nj)
                    acc[mi][nj] = __builtin_amdgcn_mfma_f32_16x16x32_bf16(
                        af[mi], bfr[nj], acc[mi][nj], 0, 0, 0);
        }
        __syncthreads();
    }

    // ---- epilogue ----
    float bias[4];
    #pragma unroll
    for (int nj = 0; nj < 4; ++nj) bias[nj] = b2f[nj * 16 + l15];

    float rn[2][4];
    #pragma unroll
    for (int mi = 0; mi < 2; ++mi)
        #pragma unroll
        for (int r = 0; r < 4; ++r) {
            float ss = 0.f;
            #pragma unroll
            for (int nj = 0; nj < 4; ++nj) {
                float v = acc[mi][nj][r] + bias[nj];
                acc[mi][nj][r] = v;
                ss += v * v;
            }
            ss += __shfl_xor(ss, 1); ss += __shfl_xor(ss, 2);
            ss += __shfl_xor(ss, 4); ss += __shfl_xor(ss, 8);
            rn[mi][r] = 1.f / fmaxf(sqrtf(ss), 1e-12f);
        }

    // z -> LDS (bf16, swizzled) + out0 store
    unsigned short* zl = Al;   // safe: last k-loop __syncthreads passed
    #pragma unroll
    for (int mi = 0; mi < 2; ++mi)
        #pragma unroll
        for (int r = 0; r < 4; ++r) {
            int lr = w * 32 + mi * 16 + hi * 4 + r;
            int grow = m0 + lr;
            float rnv = rn[mi][r];
            #pragma unroll
            for (int nj = 0; nj < 4; ++nj) {
                int c = nj * 16 + l15;
                float v = acc[mi][nj][r];
                zl[lr * 64 + (((c >> 3) ^ (lr & 7)) << 3) + (c & 7)] = f2bf(v);
                if (grow < N_NODES) out[(long)grow * OUT_DIM + c] = v * rnv;
            }
        }
    __syncthreads();

    // r = z @ Wd^T + bd via MFMA
    f32x4 racc[2] = {};
    #pragma unroll
    for (int mi = 0; mi < 2; ++mi)
        #pragma unroll
        for (int ks = 0; ks < 2; ++ks) {
            int R = w * 32 + mi * 16 + l15;
            int sc = (ks * 4 + hi) ^ (R & 7);
            bf16x8 az = *(const bf16x8*)(zl + R * 64 + sc * 8);
            int scb = (ks * 4 + hi) ^ (l15 & 7);
            bf16x8 bz = *(const bf16x8*)(WdL + l15 * 64 + scb * 8);
            racc[mi] = __builtin_amdgcn_mfma_f32_16x16x32_bf16(az, bz, racc[mi], 0, 0, 0);
        }
    const float bdv = bd[l15];
    #pragma unroll
    for (int mi = 0; mi < 2; ++mi)
        #pragma unroll
        for (int r = 0; r < 4; ++r) {
            int grow = m0 + w * 32 + mi * 16 + hi * 4 + r;
            if (grow < N_NODES)
                out[(long)N_NODES * OUT_DIM + (long)grow * RDIM + l15] = racc[mi][r] + bdv;
        }
}

extern "C" void kernel_launch(void* const* d_in, const int* in_sizes, int n_in,
                              void* d_out, int out_size, void* d_ws, size_t ws_size,
                              hipStream_t stream) {
    const float* feat  = (const float*)d_in[0];
    const int*   ei    = (const int*)  d_in[1];
    const float* ew    = (const float*)d_in[2];
    const int*   et    = (const int*)  d_in[3];
    const float* W1    = (const float*)d_in[4];
    const float* b1    = (const float*)d_in[5];
    const float* gamma = (const float*)d_in[6];
    const float* beta  = (const float*)d_in[7];
    const float* W2    = (const float*)d_in[8];
    const float* b2    = (const float*)d_in[9];
    const float* Wd    = (const float*)d_in[10];
    const float* bd    = (const float*)d_in[11];
    float* out = (float*)d_out;

    float* ws = (float*)d_ws;
    float*          h32   = ws;                                  // [N][240] f32 (dead after L4 gather)
    unsigned short* hb    = (unsigned short*)(ws + 12000000);    // [MP][512] bf16
    unsigned short* h1b   = hb + (long)MP * K2;                  // [MP][512] bf16
    float*          stats = (float*)(h1b + (long)MP * K2);       // 1024
    unsigned short* W2b   = (unsigned short*)(stats + 1024);     // [64][512] bf16
    float*          b2f   = (float*)(W2b + OUT_DIM * HID);       // 64
    unsigned short* W1b   = (unsigned short*)h32;                // aliased (used after gathers)

    // CSR scratch aliased onto h1b region (dead once gathers finish)
    int*    deg    = (int*)h1b;
    int*    rowptr = deg + 50008;
    int*    cur    = rowptr + 50008;
    int*    srcs   = cur + 50008;
    float2* wp     = (float2*)(srcs + NEDGE);

    k_init<<<(MP * IN_DIM + 255) / 256, 256, 0, stream>>>(feat, h32, hb, stats, deg);
    k_hist<<<(NEDGE + 255) / 256, 256, 0, stream>>>(ei, deg);
    k_scan<<<1, 1024, 0, stream>>>(deg, rowptr, cur);
    k_edges<<<(NEDGE + 255) / 256, 256, 0, stream>>>(ei, ew, et, cur, srcs, wp);

    k_gather<16,   0,  16,  16, 16, 1, true ><<<(N_NODES + 15) / 16, 256, 0, stream>>>(rowptr, srcs, wp, h32, hb);
    k_gather<32,  16,  48,  48, 32, 1, true ><<<(N_NODES + 7)  / 8,  256, 0, stream>>>(rowptr, srcs, wp, h32, hb);
    k_gather<64,  48, 112, 112, 64, 1, true ><<<(N_NODES + 3)  / 4,  256, 0, stream>>>(rowptr, srcs, wp, h32, hb);
    k_gather<128,112,   0, 240, 64, 2, false><<<(N_NODES + 3)  / 4,  256, 0, stream>>>(rowptr, srcs, wp, h32, hb);

    k_cvtw<<<(HID * K2 + 255) / 256, 256, 0, stream>>>(W1, W1b);

    dim3 g1(MP / 128, K2 / 128);
    k_gemm1_mfma<<<g1, 256, 0, stream>>>(hb, W1b, b1, h1b, stats);

    k_fold<<<1, 256, 0, stream>>>(stats, gamma, beta, W2, b2, W2b, b2f);

    k_head_mfma<<<MP / 128, 256, 0, stream>>>(h1b, W2b, b2f, Wd, bd, out);
}

// Round 5
// 483.374 us; speedup vs baseline: 6.5199x; 1.2554x over previous
//
#include <hip/hip_runtime.h>

#define N_NODES   50000
#define MP        50048          // rows padded to 128
#define IN_DIM    16
#define CONCAT    496
#define K2        512            // padded K for GEMM1
#define HID       512
#define OUT_DIM   64
#define RDIM      16
#define NEDGE     800000
#define H32S      48             // h32 row stride (feature 0..15, L1 out 16..47)
#define SCAN_B    196            // ceil(50000/256)

typedef __attribute__((ext_vector_type(8))) short bf16x8;
typedef __attribute__((ext_vector_type(4))) float f32x4;

static __device__ __forceinline__ unsigned short f2bf(float x) {
    union { float f; unsigned u; } v; v.f = x;
    unsigned r = v.u + 0x7fff + ((v.u >> 16) & 1);
    return (unsigned short)(r >> 16);
}
static __device__ __forceinline__ float bf2f(unsigned short b) {
    union { unsigned u; float f; } v; v.u = ((unsigned)b) << 16; return v.f;
}

#define GLDS16(gp, lp) \
    __builtin_amdgcn_global_load_lds((const __attribute__((address_space(1))) unsigned int*)(gp), \
                                     (__attribute__((address_space(3))) unsigned int*)(lp), 16, 0, 0)

// ---- init: feature -> h32[:,0:16] + hb[:,0:16]; zero pads/stats/deg --------------
__global__ __launch_bounds__(256) void k_init(const float* __restrict__ feat,
                                              float* __restrict__ h32,
                                              unsigned short* __restrict__ hb,
                                              float* __restrict__ stats,
                                              int* __restrict__ deg) {
    int idx = blockIdx.x * blockDim.x + threadIdx.x;
    if (idx < 1024) stats[idx] = 0.f;
    if (idx < N_NODES) deg[idx] = 0;
    if (idx < (MP - N_NODES) * K2) {               // zero padded rows of hb
        int r = N_NODES + (idx >> 9), c = idx & 511;
        hb[(long)r * K2 + c] = 0;
    }
    if (idx >= MP * IN_DIM) return;
    int n = idx >> 4, c = idx & 15;
    hb[(long)n * K2 + CONCAT + c] = 0;             // K pad cols 496..511
    if (n < N_NODES) {
        float x = feat[idx];
        h32[(long)n * H32S + c] = x;
        hb[(long)n * K2 + c] = f2bf(x);
    }
}

// ---- CSR build -------------------------------------------------------------------
__global__ __launch_bounds__(256) void k_hist(const int* __restrict__ ei,
                                              int* __restrict__ deg) {
    int e = blockIdx.x * blockDim.x + threadIdx.x;
    if (e < NEDGE) atomicAdd(&deg[ei[NEDGE + e]], 1);
}

__global__ __launch_bounds__(256) void k_scanA(const int* __restrict__ deg,
                                               int* __restrict__ bsum) {
    __shared__ int red[256];
    int t = threadIdx.x;
    int i = blockIdx.x * 256 + t;
    red[t] = (i < N_NODES) ? deg[i] : 0;
    __syncthreads();
    for (int d = 128; d > 0; d >>= 1) {
        if (t < d) red[t] += red[t + d];
        __syncthreads();
    }
    if (t == 0) bsum[blockIdx.x] = red[0];
}

__global__ __launch_bounds__(256) void k_scanB(const int* __restrict__ bsum,
                                               int* __restrict__ boff) {
    __shared__ int s[256];
    int t = threadIdx.x;
    s[t] = (t < SCAN_B) ? bsum[t] : 0;
    __syncthreads();
    for (int d = 1; d < 256; d <<= 1) {
        int v = (t >= d) ? s[t - d] : 0;
        __syncthreads();
        s[t] += v;
        __syncthreads();
    }
    boff[t] = (t > 0) ? s[t - 1] : 0;
}

__global__ __launch_bounds__(256) void k_scanC(const int* __restrict__ deg,
                                               const int* __restrict__ boff,
                                               int* __restrict__ rowptr,
                                               int* __restrict__ cur) {
    __shared__ int s[256];
    int t = threadIdx.x;
    int i = blockIdx.x * 256 + t;
    int v = (i < N_NODES) ? deg[i] : 0;
    s[t] = v;
    __syncthreads();
    for (int d = 1; d < 256; d <<= 1) {
        int x = (t >= d) ? s[t - d] : 0;
        __syncthreads();
        s[t] += x;
        __syncthreads();
    }
    int excl = s[t] - v + boff[blockIdx.x];
    if (i < N_NODES) { rowptr[i] = excl; cur[i] = excl; }
    if (i == N_NODES - 1) rowptr[N_NODES] = excl + v;
}

__global__ __launch_bounds__(256) void k_edges(const int* __restrict__ ei,
                                               const float* __restrict__ ew,
                                               const int* __restrict__ et,
                                               int* __restrict__ cur,
                                               int* __restrict__ srcs,
                                               float2* __restrict__ wp) {
    int e = blockIdx.x * blockDim.x + threadIdx.x;
    if (e >= NEDGE) return;
    int dst = ei[NEDGE + e];
    int pos = atomicAdd(&cur[dst], 1);
    srcs[pos] = ei[e];
    float w = ew[e];
    int ty = et[e];
    wp[pos] = make_float2(ty == 0 ? w : 0.f, ty == 1 ? w : 0.f);
}

// ---- W1 -> bf16, K-padded, aliased over dead h32 ---------------------------------
__global__ __launch_bounds__(256) void k_cvtw(const float* __restrict__ W1,
                                              unsigned short* __restrict__ W1b) {
    int idx = blockIdx.x * blockDim.x + threadIdx.x;
    if (idx >= HID * K2) return;
    int n = idx >> 9, k = idx & 511;
    W1b[idx] = (k < CONCAT) ? f2bf(W1[n * CONCAT + k]) : (unsigned short)0;
}

// ---- gather (f32 input): G lanes per dst, V floats per lane; unroll-2 ------------
template<int D, int OFF_IN, int OFF32, int OFFB, int G, int V, bool W32>
__global__ __launch_bounds__(256) void k_gather(const int* __restrict__ rowptr,
                                                const int* __restrict__ srcs,
                                                const float2* __restrict__ wp,
                                                float* __restrict__ h32,
                                                unsigned short* __restrict__ hb) {
    const int NPB = 256 / G;
    int node = blockIdx.x * NPB + threadIdx.x / G;
    if (node >= N_NODES) return;
    int lane = threadIdx.x % G;
    int p0 = rowptr[node], p1 = rowptr[node + 1];
    float a0[V] = {}, a1[V] = {}, c0[V] = {}, c1[V] = {};
    const float* hin = h32 + OFF_IN + lane * V;
    int p = p0;
    for (; p + 2 <= p1; p += 2) {
        int s0 = srcs[p], s1 = srcs[p + 1];
        float2 w0 = wp[p], w1 = wp[p + 1];
        const float* r0 = hin + (long)s0 * H32S;
        const float* r1 = hin + (long)s1 * H32S;
        #pragma unroll
        for (int v = 0; v < V; ++v) {
            float x0 = r0[v], x1 = r1[v];
            a0[v] += x0 * w0.x; a1[v] += x0 * w0.y;
            c0[v] += x1 * w1.x; c1[v] += x1 * w1.y;
        }
    }
    if (p < p1) {
        int s0 = srcs[p];
        float2 w0 = wp[p];
        const float* r0 = hin + (long)s0 * H32S;
        #pragma unroll
        for (int v = 0; v < V; ++v) {
            float x0 = r0[v];
            a0[v] += x0 * w0.x; a1[v] += x0 * w0.y;
        }
    }
    #pragma unroll
    for (int v = 0; v < V; ++v) { a0[v] += c0[v]; a1[v] += c1[v]; }

    if (W32) {
        float* o = h32 + (long)node * H32S + OFF32 + lane * V;
        #pragma unroll
        for (int v = 0; v < V; ++v) { o[v] = a0[v]; o[v + D] = a1[v]; }
    }
    unsigned short* ob = hb + (long)node * K2 + OFFB + lane * V;
    #pragma unroll
    for (int v = 0; v < V; ++v) { ob[v] = f2bf(a0[v]); ob[v + D] = f2bf(a1[v]); }
}

// ---- gather (bf16 input from hb): levels 3,4 -------------------------------------
template<int D, int OFF_IN, int OFFB, int G, int V>
__global__ __launch_bounds__(256) void k_gather_bf(const int* __restrict__ rowptr,
                                                   const int* __restrict__ srcs,
                                                   const float2* __restrict__ wp,
                                                   unsigned short* __restrict__ hb) {
    const int NPB = 256 / G;
    int node = blockIdx.x * NPB + threadIdx.x / G;
    if (node >= N_NODES) return;
    int lane = threadIdx.x % G;
    int p0 = rowptr[node], p1 = rowptr[node + 1];
    float a0[V] = {}, a1[V] = {}, c0[V] = {}, c1[V] = {};
    const unsigned short* hin = hb + OFF_IN + lane * V;
    int p = p0;
    for (; p + 2 <= p1; p += 2) {
        int s0 = srcs[p], s1 = srcs[p + 1];
        float2 w0 = wp[p], w1 = wp[p + 1];
        const unsigned short* r0 = hin + (long)s0 * K2;
        const unsigned short* r1 = hin + (long)s1 * K2;
        float x0[V], x1[V];
        if (V == 2) {
            unsigned u0 = *(const unsigned*)r0;
            unsigned u1 = *(const unsigned*)r1;
            x0[0] = bf2f((unsigned short)u0); x0[V - 1] = bf2f((unsigned short)(u0 >> 16));
            x1[0] = bf2f((unsigned short)u1); x1[V - 1] = bf2f((unsigned short)(u1 >> 16));
        } else {
            x0[0] = bf2f(*r0);
            x1[0] = bf2f(*r1);
        }
        #pragma unroll
        for (int v = 0; v < V; ++v) {
            a0[v] += x0[v] * w0.x; a1[v] += x0[v] * w0.y;
            c0[v] += x1[v] * w1.x; c1[v] += x1[v] * w1.y;
        }
    }
    if (p < p1) {
        int s0 = srcs[p];
        float2 w0 = wp[p];
        const unsigned short* r0 = hin + (long)s0 * K2;
        float x0[V];
        if (V == 2) {
            unsigned u0 = *(const unsigned*)r0;
            x0[0] = bf2f((unsigned short)u0); x0[V - 1] = bf2f((unsigned short)(u0 >> 16));
        } else {
            x0[0] = bf2f(*r0);
        }
        #pragma unroll
        for (int v = 0; v < V; ++v) {
            a0[v] += x0[v] * w0.x; a1[v] += x0[v] * w0.y;
        }
    }
    #pragma unroll
    for (int v = 0; v < V; ++v) { a0[v] += c0[v]; a1[v] += c1[v]; }

    unsigned short* ob = hb + (long)node * K2 + OFFB + lane * V;
    #pragma unroll
    for (int v = 0; v < V; ++v) { ob[v] = f2bf(a0[v]); ob[v + D] = f2bf(a1[v]); }
}

// ---- GEMM1 via MFMA: h1b = bf16(leaky_relu(hb @ W1b^T + b1)), fused col stats ----
__global__ __launch_bounds__(256) void k_gemm1_mfma(const unsigned short* __restrict__ hb,
                                                    const unsigned short* __restrict__ W1b,
                                                    const float* __restrict__ b1,
                                                    unsigned short* __restrict__ h1b,
                                                    float* __restrict__ stats) {
    __shared__ unsigned short Al[128 * 64];
    __shared__ unsigned short Bl[128 * 64];
    const int t = threadIdx.x;
    const int lane = t & 63;
    const int w = t >> 6;
    const int wr = w >> 1, wc = w & 1;
    const int m0 = blockIdx.x * 128;
    const int n0 = blockIdx.y * 128;

    f32x4 acc[4][4] = {};

    for (int kt = 0; kt < K2 / 64; ++kt) {
        const int kbase = kt * 64;
        #pragma unroll
        for (int i = 0; i < 4; ++i) {
            int tt = i * 256 + t;
            int r = tt >> 3;
            int s = tt & 7;
            int c = s ^ (r & 7);
            GLDS16(hb  + (long)(m0 + r) * K2 + kbase + c * 8, Al + tt * 8);
            GLDS16(W1b + (long)(n0 + r) * K2 + kbase + c * 8, Bl + tt * 8);
        }
        asm volatile("s_waitcnt vmcnt(0)" ::: "memory");
        __syncthreads();
        #pragma unroll
        for (int ks = 0; ks < 2; ++ks) {
            bf16x8 af[4], bfr[4];
            #pragma unroll
            for (int mi = 0; mi < 4; ++mi) {
                int R = wr * 64 + mi * 16 + (lane & 15);
                int sc = (ks * 4 + (lane >> 4)) ^ (R & 7);
                af[mi] = *(const bf16x8*)(Al + R * 64 + sc * 8);
            }
            #pragma unroll
            for (int nj = 0; nj < 4; ++nj) {
                int R = wc * 64 + nj * 16 + (lane & 15);
                int sc = (ks * 4 + (lane >> 4)) ^ (R & 7);
                bfr[nj] = *(const bf16x8*)(Bl + R * 64 + sc * 8);
            }
            #pragma unroll
            for (int mi = 0; mi < 4; ++mi)
                #pragma unroll
                for (int nj = 0; nj < 4; ++nj)
                    acc[mi][nj] = __builtin_amdgcn_mfma_f32_16x16x32_bf16(
                        af[mi], bfr[nj], acc[mi][nj], 0, 0, 0);
        }
        __syncthreads();
    }

    const int cb = n0 + wc * 64;
    float csum[4] = {0.f, 0.f, 0.f, 0.f};
    float csq[4]  = {0.f, 0.f, 0.f, 0.f};
    #pragma unroll
    for (int mi = 0; mi < 4; ++mi) {
        int rbase = m0 + wr * 64 + mi * 16 + (lane >> 4) * 4;
        #pragma unroll
        for (int nj = 0; nj < 4; ++nj) {
            int col = cb + nj * 16 + (lane & 15);
            float bias = b1[col];
            #pragma unroll
            for (int r = 0; r < 4; ++r) {
                int row = rbase + r;
                float v = acc[mi][nj][r] + bias;
                v = v > 0.f ? v : 0.2f * v;
                h1b[(long)row * HID + col] = f2bf(v);
                if (row < N_NODES) {
                    csum[nj] += v;
                    csq[nj]  += v * v;
                }
            }
        }
    }
    #pragma unroll
    for (int nj = 0; nj < 4; ++nj) {
        float s = csum[nj], q = csq[nj];
        s += __shfl_xor(s, 16); q += __shfl_xor(q, 16);
        s += __shfl_xor(s, 32); q += __shfl_xor(q, 32);
        if (lane < 16) {
            int col = cb + nj * 16 + lane;
            atomicAdd(&stats[col], s);
            atomicAdd(&stats[HID + col], q);
        }
    }
}

// ---- fold BN into W2: W2b[j][k] = bf16(W2[j][k]*scale[k]); b2f = b2 + W2@shift ---
__global__ __launch_bounds__(256) void k_fold(const float* __restrict__ stats,
                                              const float* __restrict__ gamma,
                                              const float* __restrict__ beta,
                                              const float* __restrict__ W2,
                                              const float* __restrict__ b2,
                                              unsigned short* __restrict__ W2b,
                                              float* __restrict__ b2f) {
    __shared__ float scale[HID], shift[HID];
    int t = threadIdx.x;
    for (int k = t; k < HID; k += 256) {
        float mu  = stats[k] * (1.f / N_NODES);
        float var = stats[HID + k] * (1.f / N_NODES) - mu * mu;
        var = fmaxf(var, 0.f);
        float sc = gamma[k] * rsqrtf(var + 1e-5f);
        scale[k] = sc;
        shift[k] = beta[k] - mu * sc;
    }
    __syncthreads();
    for (int idx = t; idx < OUT_DIM * HID; idx += 256) {
        int k = idx & 511;
        W2b[idx] = f2bf(W2[idx] * scale[k]);
    }
    if (t < OUT_DIM) {
        float s = b2[t];
        for (int k = 0; k < HID; ++k) s += W2[t * HID + k] * shift[k];
        b2f[t] = s;
    }
}

// ---- head via MFMA ---------------------------------------------------------------
__global__ __launch_bounds__(256) void k_head_mfma(const unsigned short* __restrict__ h1b,
                                                   const unsigned short* __restrict__ W2b,
                                                   const float* __restrict__ b2f,
                                                   const float* __restrict__ Wd,
                                                   const float* __restrict__ bd,
                                                   float* __restrict__ out) {
    __shared__ unsigned short Al[128 * 64];   // A tile; reused as z_lds in epilogue
    __shared__ unsigned short Bl[64 * 64];
    __shared__ unsigned short WdL[16 * 64];
    const int t = threadIdx.x;
    const int lane = t & 63;
    const int w = t >> 6;
    const int l15 = lane & 15, hi = lane >> 4;
    const int m0 = blockIdx.x * 128;

    for (int i = t; i < 16 * 64; i += 256) {
        int r = i >> 6, c = i & 63;
        WdL[r * 64 + (((c >> 3) ^ (r & 7)) << 3) + (c & 7)] = f2bf(Wd[i]);
    }

    f32x4 acc[2][4] = {};

    for (int kt = 0; kt < 8; ++kt) {
        const int kbase = kt * 64;
        #pragma unroll
        for (int i = 0; i < 4; ++i) {
            int tt = i * 256 + t;
            int r = tt >> 3, s = tt & 7, c = s ^ (r & 7);
            GLDS16(h1b + (long)(m0 + r) * HID + kbase + c * 8, Al + tt * 8);
        }
        #pragma unroll
        for (int i = 0; i < 2; ++i) {
            int tt = i * 256 + t;
            int r = tt >> 3, s = tt & 7, c = s ^ (r & 7);
            GLDS16(W2b + (long)r * HID + kbase + c * 8, Bl + tt * 8);
        }
        asm volatile("s_waitcnt vmcnt(0)" ::: "memory");
        __syncthreads();
        #pragma unroll
        for (int ks = 0; ks < 2; ++ks) {
            bf16x8 af[2], bfr[4];
            #pragma unroll
            for (int mi = 0; mi < 2; ++mi) {
                int R = w * 32 + mi * 16 + l15;
                int sc = (ks * 4 + hi) ^ (R & 7);
                af[mi] = *(const bf16x8*)(Al + R * 64 + sc * 8);
            }
            #pragma unroll
            for (int nj = 0; nj < 4; ++nj) {
                int R = nj * 16 + l15;
                int sc = (ks * 4 + hi) ^ (R & 7);
                bfr[nj] = *(const bf16x8*)(Bl + R * 64 + sc * 8);
            }
            #pragma unroll
            for (int mi = 0; mi < 2; ++mi)
                #pragma unroll
                for (int nj = 0; nj < 4; ++nj)
                    acc[mi][nj] = __builtin_amdgcn_mfma_f32_16x16x32_bf16(
                        af[mi], bfr[nj], acc[mi][nj], 0, 0, 0);
        }
        __syncthreads();
    }

    float bias[4];
    #pragma unroll
    for (int nj = 0; nj < 4; ++nj) bias[nj] = b2f[nj * 16 + l15];

    float rn[2][4];
    #pragma unroll
    for (int mi = 0; mi < 2; ++mi)
        #pragma unroll
        for (int r = 0; r < 4; ++r) {
            float ss = 0.f;
            #pragma unroll
            for (int nj = 0; nj < 4; ++nj) {
                float v = acc[mi][nj][r] + bias[nj];
                acc[mi][nj][r] = v;
                ss += v * v;
            }
            ss += __shfl_xor(ss, 1); ss += __shfl_xor(ss, 2);
            ss += __shfl_xor(ss, 4); ss += __shfl_xor(ss, 8);
            rn[mi][r] = 1.f / fmaxf(sqrtf(ss), 1e-12f);
        }

    unsigned short* zl = Al;
    #pragma unroll
    for (int mi = 0; mi < 2; ++mi)
        #pragma unroll
        for (int r = 0; r < 4; ++r) {
            int lr = w * 32 + mi * 16 + hi * 4 + r;
            int grow = m0 + lr;
            float rnv = rn[mi][r];
            #pragma unroll
            for (int nj = 0; nj < 4; ++nj) {
                int c = nj * 16 + l15;
                float v = acc[mi][nj][r];
                zl[lr * 64 + (((c >> 3) ^ (lr & 7)) << 3) + (c & 7)] = f2bf(v);
                if (grow < N_NODES) out[(long)grow * OUT_DIM + c] = v * rnv;
            }
        }
    __syncthreads();

    f32x4 racc[2] = {};
    #pragma unroll
    for (int mi = 0; mi < 2; ++mi)
        #pragma unroll
        for (int ks = 0; ks < 2; ++ks) {
            int R = w * 32 + mi * 16 + l15;
            int sc = (ks * 4 + hi) ^ (R & 7);
            bf16x8 az = *(const bf16x8*)(zl + R * 64 + sc * 8);
            int scb = (ks * 4 + hi) ^ (l15 & 7);
            bf16x8 bz = *(const bf16x8*)(WdL + l15 * 64 + scb * 8);
            racc[mi] = __builtin_amdgcn_mfma_f32_16x16x32_bf16(az, bz, racc[mi], 0, 0, 0);
        }
    const float bdv = bd[l15];
    #pragma unroll
    for (int mi = 0; mi < 2; ++mi)
        #pragma unroll
        for (int r = 0; r < 4; ++r) {
            int grow = m0 + w * 32 + mi * 16 + hi * 4 + r;
            if (grow < N_NODES)
                out[(long)N_NODES * OUT_DIM + (long)grow * RDIM + l15] = racc[mi][r] + bdv;
        }
}

extern "C" void kernel_launch(void* const* d_in, const int* in_sizes, int n_in,
                              void* d_out, int out_size, void* d_ws, size_t ws_size,
                              hipStream_t stream) {
    const float* feat  = (const float*)d_in[0];
    const int*   ei    = (const int*)  d_in[1];
    const float* ew    = (const float*)d_in[2];
    const int*   et    = (const int*)  d_in[3];
    const float* W1    = (const float*)d_in[4];
    const float* b1    = (const float*)d_in[5];
    const float* gamma = (const float*)d_in[6];
    const float* beta  = (const float*)d_in[7];
    const float* W2    = (const float*)d_in[8];
    const float* b2    = (const float*)d_in[9];
    const float* Wd    = (const float*)d_in[10];
    const float* bd    = (const float*)d_in[11];
    float* out = (float*)d_out;

    float* ws = (float*)d_ws;
    float*          h32   = ws;                                  // [N][48] f32 (dead after L2 gather)
    unsigned short* hb    = (unsigned short*)(ws + 2400000);     // [MP][512] bf16
    unsigned short* h1b   = hb + (long)MP * K2;                  // [MP][512] bf16
    float*          stats = (float*)(h1b + (long)MP * K2);       // 1024
    unsigned short* W2b   = (unsigned short*)(stats + 1024);     // [64][512] bf16
    float*          b2f   = (float*)(W2b + OUT_DIM * HID);       // 64
    int*            bsum  = (int*)(b2f + 64);                    // 256
    int*            boff  = bsum + 256;                          // 256
    unsigned short* W1b   = (unsigned short*)h32;                // aliased (used after gathers)

    // CSR scratch aliased onto h1b region (dead once gathers finish)
    int*    deg    = (int*)h1b;
    int*    rowptr = deg + 50008;
    int*    cur    = rowptr + 50008;
    int*    srcs   = cur + 50008;
    float2* wp     = (float2*)(srcs + NEDGE);

    k_init<<<(MP * IN_DIM + 255) / 256, 256, 0, stream>>>(feat, h32, hb, stats, deg);
    k_hist<<<(NEDGE + 255) / 256, 256, 0, stream>>>(ei, deg);
    k_scanA<<<SCAN_B, 256, 0, stream>>>(deg, bsum);
    k_scanB<<<1, 256, 0, stream>>>(bsum, boff);
    k_scanC<<<SCAN_B, 256, 0, stream>>>(deg, boff, rowptr, cur);
    k_edges<<<(NEDGE + 255) / 256, 256, 0, stream>>>(ei, ew, et, cur, srcs, wp);

    k_gather<16,  0, 16, 16, 16, 1, true ><<<(N_NODES + 15) / 16, 256, 0, stream>>>(rowptr, srcs, wp, h32, hb);
    k_gather<32, 16, -1, 48, 32, 1, false><<<(N_NODES + 7)  / 8,  256, 0, stream>>>(rowptr, srcs, wp, h32, hb);
    k_gather_bf<64,  48, 112, 64, 1><<<(N_NODES + 3) / 4, 256, 0, stream>>>(rowptr, srcs, wp, hb);
    k_gather_bf<128, 112, 240, 64, 2><<<(N_NODES + 3) / 4, 256, 0, stream>>>(rowptr, srcs, wp, hb);

    k_cvtw<<<(HID * K2 + 255) / 256, 256, 0, stream>>>(W1, W1b);

    dim3 g1(MP / 128, K2 / 128);
    k_gemm1_mfma<<<g1, 256, 0, stream>>>(hb, W1b, b1, h1b, stats);

    k_fold<<<1, 256, 0, stream>>>(stats, gamma, beta, W2, b2, W2b, b2f);

    k_head_mfma<<<MP / 128, 256, 0, stream>>>(h1b, W2b, b2f, Wd, bd, out);
}

// Round 6
// 449.966 us; speedup vs baseline: 7.0039x; 1.0742x over previous
//
#include <hip/hip_runtime.h>

#define N_NODES   50000
#define MP        50048          // rows padded to 128
#define IN_DIM    16
#define CONCAT    496
#define K2        512            // padded K for GEMM1
#define HID       512
#define OUT_DIM   64
#define RDIM      16
#define NEDGE     800000
#define H32S      48             // h32 row stride (feature 0..15, L1 out 16..47)
#define SCAN_B    196            // ceil(50000/256)
#define G1_NT     ((MP / 128) * 4)   // 1564 gemm1 tiles

typedef __attribute__((ext_vector_type(8))) short bf16x8;
typedef __attribute__((ext_vector_type(4))) float f32x4;

static __device__ __forceinline__ unsigned short f2bf(float x) {
    union { float f; unsigned u; } v; v.f = x;
    unsigned r = v.u + 0x7fff + ((v.u >> 16) & 1);
    return (unsigned short)(r >> 16);
}
static __device__ __forceinline__ float bf2f(unsigned short b) {
    union { unsigned u; float f; } v; v.u = ((unsigned)b) << 16; return v.f;
}

#define GLDS16(gp, lp) \
    __builtin_amdgcn_global_load_lds((const __attribute__((address_space(1))) unsigned int*)(gp), \
                                     (__attribute__((address_space(3))) unsigned int*)(lp), 16, 0, 0)

// ---- init: feature -> h32[:,0:16] + hb[:,0:16]; zero pads/stats/deg --------------
__global__ __launch_bounds__(256) void k_init(const float* __restrict__ feat,
                                              float* __restrict__ h32,
                                              unsigned short* __restrict__ hb,
                                              float* __restrict__ stats,
                                              int* __restrict__ deg) {
    int idx = blockIdx.x * blockDim.x + threadIdx.x;
    if (idx < 1024) stats[idx] = 0.f;
    if (idx < N_NODES) deg[idx] = 0;
    if (idx < (MP - N_NODES) * K2) {               // zero padded rows of hb
        int r = N_NODES + (idx >> 9), c = idx & 511;
        hb[(long)r * K2 + c] = 0;
    }
    if (idx >= MP * IN_DIM) return;
    int n = idx >> 4, c = idx & 15;
    hb[(long)n * K2 + CONCAT + c] = 0;             // K pad cols 496..511
    if (n < N_NODES) {
        float x = feat[idx];
        h32[(long)n * H32S + c] = x;
        hb[(long)n * K2 + c] = f2bf(x);
    }
}

// ---- CSR build -------------------------------------------------------------------
__global__ __launch_bounds__(256) void k_hist(const int* __restrict__ ei,
                                              int* __restrict__ deg) {
    int e = blockIdx.x * blockDim.x + threadIdx.x;
    if (e < NEDGE) atomicAdd(&deg[ei[NEDGE + e]], 1);
}

__global__ __launch_bounds__(256) void k_scanA(const int* __restrict__ deg,
                                               int* __restrict__ bsum) {
    __shared__ int red[256];
    int t = threadIdx.x;
    int i = blockIdx.x * 256 + t;
    red[t] = (i < N_NODES) ? deg[i] : 0;
    __syncthreads();
    for (int d = 128; d > 0; d >>= 1) {
        if (t < d) red[t] += red[t + d];
        __syncthreads();
    }
    if (t == 0) bsum[blockIdx.x] = red[0];
}

__global__ __launch_bounds__(256) void k_scanB(const int* __restrict__ bsum,
                                               int* __restrict__ boff) {
    __shared__ int s[256];
    int t = threadIdx.x;
    s[t] = (t < SCAN_B) ? bsum[t] : 0;
    __syncthreads();
    for (int d = 1; d < 256; d <<= 1) {
        int v = (t >= d) ? s[t - d] : 0;
        __syncthreads();
        s[t] += v;
        __syncthreads();
    }
    boff[t] = (t > 0) ? s[t - 1] : 0;
}

__global__ __launch_bounds__(256) void k_scanC(const int* __restrict__ deg,
                                               const int* __restrict__ boff,
                                               int* __restrict__ rowptr,
                                               int* __restrict__ cur) {
    __shared__ int s[256];
    int t = threadIdx.x;
    int i = blockIdx.x * 256 + t;
    int v = (i < N_NODES) ? deg[i] : 0;
    s[t] = v;
    __syncthreads();
    for (int d = 1; d < 256; d <<= 1) {
        int x = (t >= d) ? s[t - d] : 0;
        __syncthreads();
        s[t] += x;
        __syncthreads();
    }
    int excl = s[t] - v + boff[blockIdx.x];
    if (i < N_NODES) { rowptr[i] = excl; cur[i] = excl; }
    if (i == N_NODES - 1) rowptr[N_NODES] = excl + v;
}

// ---- edge perm: one packed 16B record per edge {src, w0, w1, pad} ----------------
__global__ __launch_bounds__(256) void k_edges(const int* __restrict__ ei,
                                               const float* __restrict__ ew,
                                               const int* __restrict__ et,
                                               int* __restrict__ cur,
                                               int4* __restrict__ ed) {
    int e = blockIdx.x * blockDim.x + threadIdx.x;
    if (e >= NEDGE) return;
    int dst = ei[NEDGE + e];
    int pos = atomicAdd(&cur[dst], 1);
    float w = ew[e];
    int ty = et[e];
    ed[pos] = make_int4(ei[e],
                        __float_as_int(ty == 0 ? w : 0.f),
                        __float_as_int(ty == 1 ? w : 0.f), 0);
}

// ---- W1 -> bf16, K-padded, aliased over dead h32 ---------------------------------
__global__ __launch_bounds__(256) void k_cvtw(const float* __restrict__ W1,
                                              unsigned short* __restrict__ W1b) {
    int idx = blockIdx.x * blockDim.x + threadIdx.x;
    if (idx >= HID * K2) return;
    int n = idx >> 9, k = idx & 511;
    W1b[idx] = (k < CONCAT) ? f2bf(W1[n * CONCAT + k]) : (unsigned short)0;
}

// ---- gather (f32 input): G lanes per dst, V floats per lane; unroll-2 ------------
template<int D, int OFF_IN, int OFF32, int OFFB, int G, int V, bool W32>
__global__ __launch_bounds__(256) void k_gather(const int* __restrict__ rowptr,
                                                const int4* __restrict__ ed,
                                                float* __restrict__ h32,
                                                unsigned short* __restrict__ hb) {
    const int NPB = 256 / G;
    int node = blockIdx.x * NPB + threadIdx.x / G;
    if (node >= N_NODES) return;
    int lane = threadIdx.x % G;
    int p0 = rowptr[node], p1 = rowptr[node + 1];
    float a0[V] = {}, a1[V] = {}, c0[V] = {}, c1[V] = {};
    const float* hin = h32 + OFF_IN + lane * V;
    int p = p0;
    for (; p + 2 <= p1; p += 2) {
        int4 e0 = ed[p], e1 = ed[p + 1];
        const float* r0 = hin + (long)e0.x * H32S;
        const float* r1 = hin + (long)e1.x * H32S;
        float w00 = __int_as_float(e0.y), w01 = __int_as_float(e0.z);
        float w10 = __int_as_float(e1.y), w11 = __int_as_float(e1.z);
        #pragma unroll
        for (int v = 0; v < V; ++v) {
            float x0 = r0[v], x1 = r1[v];
            a0[v] += x0 * w00; a1[v] += x0 * w01;
            c0[v] += x1 * w10; c1[v] += x1 * w11;
        }
    }
    if (p < p1) {
        int4 e0 = ed[p];
        const float* r0 = hin + (long)e0.x * H32S;
        float w00 = __int_as_float(e0.y), w01 = __int_as_float(e0.z);
        #pragma unroll
        for (int v = 0; v < V; ++v) {
            float x0 = r0[v];
            a0[v] += x0 * w00; a1[v] += x0 * w01;
        }
    }
    #pragma unroll
    for (int v = 0; v < V; ++v) { a0[v] += c0[v]; a1[v] += c1[v]; }

    if (W32) {
        float* o = h32 + (long)node * H32S + OFF32 + lane * V;
        #pragma unroll
        for (int v = 0; v < V; ++v) { o[v] = a0[v]; o[v + D] = a1[v]; }
    }
    unsigned short* ob = hb + (long)node * K2 + OFFB + lane * V;
    #pragma unroll
    for (int v = 0; v < V; ++v) { ob[v] = f2bf(a0[v]); ob[v + D] = f2bf(a1[v]); }
}

// ---- gather (bf16 input from hb): levels 3,4 -------------------------------------
template<int D, int OFF_IN, int OFFB, int G, int V>
__global__ __launch_bounds__(256) void k_gather_bf(const int* __restrict__ rowptr,
                                                   const int4* __restrict__ ed,
                                                   unsigned short* __restrict__ hb) {
    const int NPB = 256 / G;
    int node = blockIdx.x * NPB + threadIdx.x / G;
    if (node >= N_NODES) return;
    int lane = threadIdx.x % G;
    int p0 = rowptr[node], p1 = rowptr[node + 1];
    float a0[V] = {}, a1[V] = {}, c0[V] = {}, c1[V] = {};
    const unsigned short* hin = hb + OFF_IN + lane * V;
    int p = p0;
    for (; p + 2 <= p1; p += 2) {
        int4 e0 = ed[p], e1 = ed[p + 1];
        const unsigned short* r0 = hin + (long)e0.x * K2;
        const unsigned short* r1 = hin + (long)e1.x * K2;
        float w00 = __int_as_float(e0.y), w01 = __int_as_float(e0.z);
        float w10 = __int_as_float(e1.y), w11 = __int_as_float(e1.z);
        float x0[V], x1[V];
        if (V == 2) {
            unsigned u0 = *(const unsigned*)r0;
            unsigned u1 = *(const unsigned*)r1;
            x0[0] = bf2f((unsigned short)u0); x0[V - 1] = bf2f((unsigned short)(u0 >> 16));
            x1[0] = bf2f((unsigned short)u1); x1[V - 1] = bf2f((unsigned short)(u1 >> 16));
        } else {
            x0[0] = bf2f(*r0);
            x1[0] = bf2f(*r1);
        }
        #pragma unroll
        for (int v = 0; v < V; ++v) {
            a0[v] += x0[v] * w00; a1[v] += x0[v] * w01;
            c0[v] += x1[v] * w10; c1[v] += x1[v] * w11;
        }
    }
    if (p < p1) {
        int4 e0 = ed[p];
        const unsigned short* r0 = hin + (long)e0.x * K2;
        float w00 = __int_as_float(e0.y), w01 = __int_as_float(e0.z);
        float x0[V];
        if (V == 2) {
            unsigned u0 = *(const unsigned*)r0;
            x0[0] = bf2f((unsigned short)u0); x0[V - 1] = bf2f((unsigned short)(u0 >> 16));
        } else {
            x0[0] = bf2f(*r0);
        }
        #pragma unroll
        for (int v = 0; v < V; ++v) {
            a0[v] += x0[v] * w00; a1[v] += x0[v] * w01;
        }
    }
    #pragma unroll
    for (int v = 0; v < V; ++v) { a0[v] += c0[v]; a1[v] += c1[v]; }

    unsigned short* ob = hb + (long)node * K2 + OFFB + lane * V;
    #pragma unroll
    for (int v = 0; v < V; ++v) { ob[v] = f2bf(a0[v]); ob[v + D] = f2bf(a1[v]); }
}

// ---- GEMM1 via MFMA, 2-phase prefetch dbuf + XCD swizzle -------------------------
#define STAGE_G1(kb, AL, BL) do { \
    _Pragma("unroll") \
    for (int i_ = 0; i_ < 4; ++i_) { \
        int tt = i_ * 256 + t; \
        int r = tt >> 3, s_ = tt & 7, c = s_ ^ (r & 7); \
        GLDS16(hb  + (long)(m0 + r) * K2 + (kb) + c * 8, (AL) + tt * 8); \
        GLDS16(W1b + (long)(n0 + r) * K2 + (kb) + c * 8, (BL) + tt * 8); \
    } } while (0)

__global__ __launch_bounds__(256) void k_gemm1_mfma(const unsigned short* __restrict__ hb,
                                                    const unsigned short* __restrict__ W1b,
                                                    const float* __restrict__ b1,
                                                    unsigned short* __restrict__ h1b,
                                                    float* __restrict__ stats) {
    __shared__ unsigned short Al[2][128 * 64];
    __shared__ unsigned short Bl[2][128 * 64];
    const int t = threadIdx.x;
    const int lane = t & 63;
    const int w = t >> 6;
    const int wr = w >> 1, wc = w & 1;

    // bijective XCD swizzle: col-inner logical order, contiguous chunk per XCD
    const int q = G1_NT / 8, rem = G1_NT % 8;     // 195, 4
    int f = blockIdx.x;
    int xcd = f & 7, pos = f >> 3;
    int logical = (xcd < rem ? xcd * (q + 1) : rem * (q + 1) + (xcd - rem) * q) + pos;
    const int m0 = (logical >> 2) * 128;
    const int n0 = (logical & 3) * 128;

    f32x4 acc[4][4] = {};

    STAGE_G1(0, Al[0], Bl[0]);
    __syncthreads();
    int cur = 0;
    for (int kt = 0; kt < 8; ++kt) {
        if (kt < 7) STAGE_G1((kt + 1) * 64, Al[cur ^ 1], Bl[cur ^ 1]);
        __builtin_amdgcn_sched_barrier(0);
        #pragma unroll
        for (int ks = 0; ks < 2; ++ks) {
            bf16x8 af[4], bfr[4];
            #pragma unroll
            for (int mi = 0; mi < 4; ++mi) {
                int R = wr * 64 + mi * 16 + (lane & 15);
                int sc = (ks * 4 + (lane >> 4)) ^ (R & 7);
                af[mi] = *(const bf16x8*)(Al[cur] + R * 64 + sc * 8);
            }
            #pragma unroll
            for (int nj = 0; nj < 4; ++nj) {
                int R = wc * 64 + nj * 16 + (lane & 15);
                int sc = (ks * 4 + (lane >> 4)) ^ (R & 7);
                bfr[nj] = *(const bf16x8*)(Bl[cur] + R * 64 + sc * 8);
            }
            #pragma unroll
            for (int mi = 0; mi < 4; ++mi)
                #pragma unroll
                for (int nj = 0; nj < 4; ++nj)
                    acc[mi][nj] = __builtin_amdgcn_mfma_f32_16x16x32_bf16(
                        af[mi], bfr[nj], acc[mi][nj], 0, 0, 0);
        }
        __syncthreads();   // drains this iter's prefetch (vmcnt 0) + barrier
        cur ^= 1;
    }

    const int cb = n0 + wc * 64;
    float csum[4] = {0.f, 0.f, 0.f, 0.f};
    float csq[4]  = {0.f, 0.f, 0.f, 0.f};
    #pragma unroll
    for (int mi = 0; mi < 4; ++mi) {
        int rbase = m0 + wr * 64 + mi * 16 + (lane >> 4) * 4;
        #pragma unroll
        for (int nj = 0; nj < 4; ++nj) {
            int col = cb + nj * 16 + (lane & 15);
            float bias = b1[col];
            #pragma unroll
            for (int r = 0; r < 4; ++r) {
                int row = rbase + r;
                float v = acc[mi][nj][r] + bias;
                v = v > 0.f ? v : 0.2f * v;
                h1b[(long)row * HID + col] = f2bf(v);
                if (row < N_NODES) {
                    csum[nj] += v;
                    csq[nj]  += v * v;
                }
            }
        }
    }
    #pragma unroll
    for (int nj = 0; nj < 4; ++nj) {
        float s = csum[nj], qq = csq[nj];
        s += __shfl_xor(s, 16); qq += __shfl_xor(qq, 16);
        s += __shfl_xor(s, 32); qq += __shfl_xor(qq, 32);
        if (lane < 16) {
            int col = cb + nj * 16 + lane;
            atomicAdd(&stats[col], s);
            atomicAdd(&stats[HID + col], qq);
        }
    }
}

// ---- fold BN into W2: W2b[j][k] = bf16(W2[j][k]*scale[k]); b2f = b2 + W2@shift ---
__global__ __launch_bounds__(256) void k_fold(const float* __restrict__ stats,
                                              const float* __restrict__ gamma,
                                              const float* __restrict__ beta,
                                              const float* __restrict__ W2,
                                              const float* __restrict__ b2,
                                              unsigned short* __restrict__ W2b,
                                              float* __restrict__ b2f) {
    __shared__ float scale[HID], shift[HID];
    int t = threadIdx.x;
    for (int k = t; k < HID; k += 256) {
        float mu  = stats[k] * (1.f / N_NODES);
        float var = stats[HID + k] * (1.f / N_NODES) - mu * mu;
        var = fmaxf(var, 0.f);
        float sc = gamma[k] * rsqrtf(var + 1e-5f);
        scale[k] = sc;
        shift[k] = beta[k] - mu * sc;
    }
    __syncthreads();
    for (int idx = t; idx < OUT_DIM * HID; idx += 256) {
        int k = idx & 511;
        W2b[idx] = f2bf(W2[idx] * scale[k]);
    }
    if (t < OUT_DIM) {
        float s = b2[t];
        for (int k = 0; k < HID; ++k) s += W2[t * HID + k] * shift[k];
        b2f[t] = s;
    }
}

// ---- head via MFMA, 2-phase prefetch dbuf ----------------------------------------
#define STAGE_HD(kb, AL, BL) do { \
    _Pragma("unroll") \
    for (int i_ = 0; i_ < 4; ++i_) { \
        int tt = i_ * 256 + t; \
        int r = tt >> 3, s_ = tt & 7, c = s_ ^ (r & 7); \
        GLDS16(h1b + (long)(m0 + r) * HID + (kb) + c * 8, (AL) + tt * 8); \
    } \
    _Pragma("unroll") \
    for (int i_ = 0; i_ < 2; ++i_) { \
        int tt = i_ * 256 + t; \
        int r = tt >> 3, s_ = tt & 7, c = s_ ^ (r & 7); \
        GLDS16(W2b + (long)r * HID + (kb) + c * 8, (BL) + tt * 8); \
    } } while (0)

__global__ __launch_bounds__(256) void k_head_mfma(const unsigned short* __restrict__ h1b,
                                                   const unsigned short* __restrict__ W2b,
                                                   const float* __restrict__ b2f,
                                                   const float* __restrict__ Wd,
                                                   const float* __restrict__ bd,
                                                   float* __restrict__ out) {
    __shared__ unsigned short Al[2][128 * 64];   // Al[0] reused as z_lds in epilogue
    __shared__ unsigned short Bl[2][64 * 64];
    __shared__ unsigned short WdL[16 * 64];
    const int t = threadIdx.x;
    const int lane = t & 63;
    const int w = t >> 6;
    const int l15 = lane & 15, hi = lane >> 4;
    const int m0 = blockIdx.x * 128;

    for (int i = t; i < 16 * 64; i += 256) {
        int r = i >> 6, c = i & 63;
        WdL[r * 64 + (((c >> 3) ^ (r & 7)) << 3) + (c & 7)] = f2bf(Wd[i]);
    }

    f32x4 acc[2][4] = {};

    STAGE_HD(0, Al[0], Bl[0]);
    __syncthreads();
    int cur = 0;
    for (int kt = 0; kt < 8; ++kt) {
        if (kt < 7) STAGE_HD((kt + 1) * 64, Al[cur ^ 1], Bl[cur ^ 1]);
        __builtin_amdgcn_sched_barrier(0);
        #pragma unroll
        for (int ks = 0; ks < 2; ++ks) {
            bf16x8 af[2], bfr[4];
            #pragma unroll
            for (int mi = 0; mi < 2; ++mi) {
                int R = w * 32 + mi * 16 + l15;
                int sc = (ks * 4 + hi) ^ (R & 7);
                af[mi] = *(const bf16x8*)(Al[cur] + R * 64 + sc * 8);
            }
            #pragma unroll
            for (int nj = 0; nj < 4; ++nj) {
                int R = nj * 16 + l15;
                int sc = (ks * 4 + hi) ^ (R & 7);
                bfr[nj] = *(const bf16x8*)(Bl[cur] + R * 64 + sc * 8);
            }
            #pragma unroll
            for (int mi = 0; mi < 2; ++mi)
                #pragma unroll
                for (int nj = 0; nj < 4; ++nj)
                    acc[mi][nj] = __builtin_amdgcn_mfma_f32_16x16x32_bf16(
                        af[mi], bfr[nj], acc[mi][nj], 0, 0, 0);
        }
        __syncthreads();
        cur ^= 1;
    }

    float bias[4];
    #pragma unroll
    for (int nj = 0; nj < 4; ++nj) bias[nj] = b2f[nj * 16 + l15];

    float rn[2][4];
    #pragma unroll
    for (int mi = 0; mi < 2; ++mi)
        #pragma unroll
        for (int r = 0; r < 4; ++r) {
            float ss = 0.f;
            #pragma unroll
            for (int nj = 0; nj < 4; ++nj) {
                float v = acc[mi][nj][r] + bias[nj];
                acc[mi][nj][r] = v;
                ss += v * v;
            }
            ss += __shfl_xor(ss, 1); ss += __shfl_xor(ss, 2);
            ss += __shfl_xor(ss, 4); ss += __shfl_xor(ss, 8);
            rn[mi][r] = 1.f / fmaxf(sqrtf(ss), 1e-12f);
        }

    unsigned short* zl = Al[0];
    #pragma unroll
    for (int mi = 0; mi < 2; ++mi)
        #pragma unroll
        for (int r = 0; r < 4; ++r) {
            int lr = w * 32 + mi * 16 + hi * 4 + r;
            int grow = m0 + lr;
            float rnv = rn[mi][r];
            #pragma unroll
            for (int nj = 0; nj < 4; ++nj) {
                int c = nj * 16 + l15;
                float v = acc[mi][nj][r];
                zl[lr * 64 + (((c >> 3) ^ (lr & 7)) << 3) + (c & 7)] = f2bf(v);
                if (grow < N_NODES) out[(long)grow * OUT_DIM + c] = v * rnv;
            }
        }
    __syncthreads();

    f32x4 racc[2] = {};
    #pragma unroll
    for (int mi = 0; mi < 2; ++mi)
        #pragma unroll
        for (int ks = 0; ks < 2; ++ks) {
            int R = w * 32 + mi * 16 + l15;
            int sc = (ks * 4 + hi) ^ (R & 7);
            bf16x8 az = *(const bf16x8*)(zl + R * 64 + sc * 8);
            int scb = (ks * 4 + hi) ^ (l15 & 7);
            bf16x8 bz = *(const bf16x8*)(WdL + l15 * 64 + scb * 8);
            racc[mi] = __builtin_amdgcn_mfma_f32_16x16x32_bf16(az, bz, racc[mi], 0, 0, 0);
        }
    const float bdv = bd[l15];
    #pragma unroll
    for (int mi = 0; mi < 2; ++mi)
        #pragma unroll
        for (int r = 0; r < 4; ++r) {
            int grow = m0 + w * 32 + mi * 16 + hi * 4 + r;
            if (grow < N_NODES)
                out[(long)N_NODES * OUT_DIM + (long)grow * RDIM + l15] = racc[mi][r] + bdv;
        }
}

extern "C" void kernel_launch(void* const* d_in, const int* in_sizes, int n_in,
                              void* d_out, int out_size, void* d_ws, size_t ws_size,
                              hipStream_t stream) {
    const float* feat  = (const float*)d_in[0];
    const int*   ei    = (const int*)  d_in[1];
    const float* ew    = (const float*)d_in[2];
    const int*   et    = (const int*)  d_in[3];
    const float* W1    = (const float*)d_in[4];
    const float* b1    = (const float*)d_in[5];
    const float* gamma = (const float*)d_in[6];
    const float* beta  = (const float*)d_in[7];
    const float* W2    = (const float*)d_in[8];
    const float* b2    = (const float*)d_in[9];
    const float* Wd    = (const float*)d_in[10];
    const float* bd    = (const float*)d_in[11];
    float* out = (float*)d_out;

    float* ws = (float*)d_ws;
    float*          h32   = ws;                                  // [N][48] f32 (dead after L2 gather)
    unsigned short* hb    = (unsigned short*)(ws + 2400000);     // [MP][512] bf16
    unsigned short* h1b   = hb + (long)MP * K2;                  // [MP][512] bf16
    float*          stats = (float*)(h1b + (long)MP * K2);       // 1024
    unsigned short* W2b   = (unsigned short*)(stats + 1024);     // [64][512] bf16
    float*          b2f   = (float*)(W2b + OUT_DIM * HID);       // 64
    int*            bsum  = (int*)(b2f + 64);                    // 256
    int*            boff  = bsum + 256;                          // 256
    unsigned short* W1b   = (unsigned short*)h32;                // aliased (used after gathers)

    // CSR scratch aliased onto h1b region (dead once gathers finish)
    int*    deg    = (int*)h1b;
    int*    rowptr = deg + 50008;
    int*    cur    = rowptr + 50008;
    int4*   ed     = (int4*)(cur + 50008);     // 16B-aligned: 150024 ints offset

    k_init<<<(MP * IN_DIM + 255) / 256, 256, 0, stream>>>(feat, h32, hb, stats, deg);
    k_hist<<<(NEDGE + 255) / 256, 256, 0, stream>>>(ei, deg);
    k_scanA<<<SCAN_B, 256, 0, stream>>>(deg, bsum);
    k_scanB<<<1, 256, 0, stream>>>(bsum, boff);
    k_scanC<<<SCAN_B, 256, 0, stream>>>(deg, boff, rowptr, cur);
    k_edges<<<(NEDGE + 255) / 256, 256, 0, stream>>>(ei, ew, et, cur, ed);

    k_gather<16,  0, 16, 16, 16, 1, true ><<<(N_NODES + 15) / 16, 256, 0, stream>>>(rowptr, ed, h32, hb);
    k_gather<32, 16, -1, 48, 32, 1, false><<<(N_NODES + 7)  / 8,  256, 0, stream>>>(rowptr, ed, h32, hb);
    k_gather_bf<64,  48, 112, 64, 1><<<(N_NODES + 3) / 4, 256, 0, stream>>>(rowptr, ed, hb);
    k_gather_bf<128, 112, 240, 64, 2><<<(N_NODES + 3) / 4, 256, 0, stream>>>(rowptr, ed, hb);

    k_cvtw<<<(HID * K2 + 255) / 256, 256, 0, stream>>>(W1, W1b);

    k_gemm1_mfma<<<G1_NT, 256, 0, stream>>>(hb, W1b, b1, h1b, stats);

    k_fold<<<1, 256, 0, stream>>>(stats, gamma, beta, W2, b2, W2b, b2f);

    k_head_mfma<<<MP / 128, 256, 0, stream>>>(h1b, W2b, b2f, Wd, bd, out);
}

// Round 7
// 413.551 us; speedup vs baseline: 7.6207x; 1.0881x over previous
//
#include <hip/hip_runtime.h>

#define N_NODES   50000
#define MP        50048          // rows padded to 128
#define IN_DIM    16
#define CONCAT    496
#define K2        512            // padded K for GEMM1
#define HID       512
#define OUT_DIM   64
#define RDIM      16
#define NEDGE     800000
#define H32S      48             // h32 row stride (feature 0..15, L1 out 16..47)
#define SCAN_B    196            // ceil(50000/256)
#define G1_NT     ((MP / 128) * 4)   // 1564 gemm1 tiles

typedef __attribute__((ext_vector_type(8))) short bf16x8;
typedef __attribute__((ext_vector_type(4))) float f32x4;

static __device__ __forceinline__ unsigned short f2bf(float x) {
    union { float f; unsigned u; } v; v.f = x;
    unsigned r = v.u + 0x7fff + ((v.u >> 16) & 1);
    return (unsigned short)(r >> 16);
}
static __device__ __forceinline__ float bf2f(unsigned short b) {
    union { unsigned u; float f; } v; v.u = ((unsigned)b) << 16; return v.f;
}
static __device__ __forceinline__ unsigned packbf2(float a, float b) {
    return (unsigned)f2bf(a) | ((unsigned)f2bf(b) << 16);
}
// decode packed weight: {w0, w1} from w_bits|type<<31
static __device__ __forceinline__ float2 decw(int wbi) {
    unsigned wb = (unsigned)wbi;
    float w = __uint_as_float(wb & 0x7fffffffu);
    return (wb >> 31) ? make_float2(0.f, w) : make_float2(w, 0.f);
}

#define GLDS16(gp, lp) \
    __builtin_amdgcn_global_load_lds((const __attribute__((address_space(1))) unsigned int*)(gp), \
                                     (__attribute__((address_space(3))) unsigned int*)(lp), 16, 0, 0)

// ---- init: feature -> h32/hb; zero pads/stats/deg; W1 -> bf16 (fused cvtw) -------
__global__ __launch_bounds__(256) void k_init(const float* __restrict__ feat,
                                              const float* __restrict__ W1,
                                              float* __restrict__ h32,
                                              unsigned short* __restrict__ hb,
                                              unsigned short* __restrict__ W1b,
                                              float* __restrict__ stats,
                                              int* __restrict__ deg) {
    int idx = blockIdx.x * blockDim.x + threadIdx.x;
    if (idx < 1024) stats[idx] = 0.f;
    if (idx < N_NODES) deg[idx] = 0;
    if (idx < HID * K2) {                          // W1 -> bf16, K-padded
        int n = idx >> 9, k = idx & 511;
        W1b[idx] = (k < CONCAT) ? f2bf(W1[n * CONCAT + k]) : (unsigned short)0;
    }
    if (idx < (MP - N_NODES) * K2) {               // zero padded rows of hb
        int r = N_NODES + (idx >> 9), c = idx & 511;
        hb[(long)r * K2 + c] = 0;
    }
    if (idx >= MP * IN_DIM) return;
    int n = idx >> 4, c = idx & 15;
    hb[(long)n * K2 + CONCAT + c] = 0;             // K pad cols 496..511
    if (n < N_NODES) {
        float x = feat[idx];
        h32[(long)n * H32S + c] = x;
        hb[(long)n * K2 + c] = f2bf(x);
    }
}

// ---- CSR build -------------------------------------------------------------------
__global__ __launch_bounds__(256) void k_hist(const int* __restrict__ ei,
                                              int* __restrict__ deg) {
    int e = blockIdx.x * blockDim.x + threadIdx.x;
    if (e < NEDGE) atomicAdd(&deg[ei[NEDGE + e]], 1);
}

__global__ __launch_bounds__(256) void k_scanA(const int* __restrict__ deg,
                                               int* __restrict__ bsum) {
    __shared__ int red[256];
    int t = threadIdx.x;
    int i = blockIdx.x * 256 + t;
    red[t] = (i < N_NODES) ? deg[i] : 0;
    __syncthreads();
    for (int d = 128; d > 0; d >>= 1) {
        if (t < d) red[t] += red[t + d];
        __syncthreads();
    }
    if (t == 0) bsum[blockIdx.x] = red[0];
}

__global__ __launch_bounds__(256) void k_scanB(const int* __restrict__ bsum,
                                               int* __restrict__ boff) {
    __shared__ int s[256];
    int t = threadIdx.x;
    s[t] = (t < SCAN_B) ? bsum[t] : 0;
    __syncthreads();
    for (int d = 1; d < 256; d <<= 1) {
        int v = (t >= d) ? s[t - d] : 0;
        __syncthreads();
        s[t] += v;
        __syncthreads();
    }
    boff[t] = (t > 0) ? s[t - 1] : 0;
}

__global__ __launch_bounds__(256) void k_scanC(const int* __restrict__ deg,
                                               const int* __restrict__ boff,
                                               int* __restrict__ rowptr,
                                               int* __restrict__ cur) {
    __shared__ int s[256];
    int t = threadIdx.x;
    int i = blockIdx.x * 256 + t;
    int v = (i < N_NODES) ? deg[i] : 0;
    s[t] = v;
    __syncthreads();
    for (int d = 1; d < 256; d <<= 1) {
        int x = (t >= d) ? s[t - d] : 0;
        __syncthreads();
        s[t] += x;
        __syncthreads();
    }
    int excl = s[t] - v + boff[blockIdx.x];
    if (i < N_NODES) { rowptr[i] = excl; cur[i] = excl; }
    if (i == N_NODES - 1) rowptr[N_NODES] = excl + v;
}

// ---- edge positions: pos[e] = slot in CSR order (coalesced write) ----------------
__global__ __launch_bounds__(256) void k_pos(const int* __restrict__ ei,
                                             int* __restrict__ cur,
                                             int* __restrict__ pos) {
    int e = blockIdx.x * blockDim.x + threadIdx.x;
    if (e >= NEDGE) return;
    pos[e] = atomicAdd(&cur[ei[NEDGE + e]], 1);
}

// ---- edge scatter: 8B packed record {src, w|type<<31} at pos[e] ------------------
__global__ __launch_bounds__(256) void k_scat(const int* __restrict__ ei,
                                              const float* __restrict__ ew,
                                              const int* __restrict__ et,
                                              const int* __restrict__ pos,
                                              int2* __restrict__ ed8) {
    int e = blockIdx.x * blockDim.x + threadIdx.x;
    if (e >= NEDGE) return;
    unsigned wb = (__float_as_uint(ew[e]) & 0x7fffffffu) | ((unsigned)et[e] << 31);
    ed8[pos[e]] = make_int2(ei[e], (int)wb);
}

// ---- gather (f32 input): G lanes per dst, V floats per lane; unroll-4 ------------
template<int D, int OFF_IN, int OFF32, int OFFB, int G, int V, bool W32>
__global__ __launch_bounds__(256) void k_gather(const int* __restrict__ rowptr,
                                                const int2* __restrict__ ed8,
                                                float* __restrict__ h32,
                                                unsigned short* __restrict__ hb) {
    const int NPB = 256 / G;
    int node = blockIdx.x * NPB + threadIdx.x / G;
    if (node >= N_NODES) return;
    int lane = threadIdx.x % G;
    int p0 = rowptr[node], p1 = rowptr[node + 1];
    float a0[V] = {}, a1[V] = {}, c0[V] = {}, c1[V] = {};
    const float* hin = h32 + OFF_IN + lane * V;
    int p = p0;
    for (; p + 4 <= p1; p += 4) {
        int2 E0 = ed8[p], E1 = ed8[p + 1], E2 = ed8[p + 2], E3 = ed8[p + 3];
        const float* R0 = hin + (long)E0.x * H32S;
        const float* R1 = hin + (long)E1.x * H32S;
        const float* R2 = hin + (long)E2.x * H32S;
        const float* R3 = hin + (long)E3.x * H32S;
        float x0[V], x1[V], x2[V], x3[V];
        #pragma unroll
        for (int v = 0; v < V; ++v) { x0[v] = R0[v]; x1[v] = R1[v]; x2[v] = R2[v]; x3[v] = R3[v]; }
        float2 w0 = decw(E0.y), w1 = decw(E1.y), w2 = decw(E2.y), w3 = decw(E3.y);
        #pragma unroll
        for (int v = 0; v < V; ++v) {
            a0[v] += x0[v] * w0.x; a1[v] += x0[v] * w0.y;
            c0[v] += x1[v] * w1.x; c1[v] += x1[v] * w1.y;
            a0[v] += x2[v] * w2.x; a1[v] += x2[v] * w2.y;
            c0[v] += x3[v] * w3.x; c1[v] += x3[v] * w3.y;
        }
    }
    for (; p < p1; ++p) {
        int2 E0 = ed8[p];
        const float* R0 = hin + (long)E0.x * H32S;
        float2 w0 = decw(E0.y);
        #pragma unroll
        for (int v = 0; v < V; ++v) {
            float x = R0[v];
            a0[v] += x * w0.x; a1[v] += x * w0.y;
        }
    }
    #pragma unroll
    for (int v = 0; v < V; ++v) { a0[v] += c0[v]; a1[v] += c1[v]; }

    if (W32) {
        float* o = h32 + (long)node * H32S + OFF32 + lane * V;
        #pragma unroll
        for (int v = 0; v < V; ++v) { o[v] = a0[v]; o[v + D] = a1[v]; }
    }
    unsigned short* ob = hb + (long)node * K2 + OFFB + lane * V;
    #pragma unroll
    for (int v = 0; v < V; ++v) { ob[v] = f2bf(a0[v]); ob[v + D] = f2bf(a1[v]); }
}

// ---- gather (bf16 input from hb): V==2, 4B packed loads/stores; unroll-4 ---------
template<int D, int OFF_IN, int OFFB, int G>
__global__ __launch_bounds__(256) void k_gather_bf(const int* __restrict__ rowptr,
                                                   const int2* __restrict__ ed8,
                                                   unsigned short* __restrict__ hb) {
    const int NPB = 256 / G;
    int node = blockIdx.x * NPB + threadIdx.x / G;
    if (node >= N_NODES) return;
    int lane = threadIdx.x % G;
    int p0 = rowptr[node], p1 = rowptr[node + 1];
    float a00 = 0.f, a01 = 0.f, a10 = 0.f, a11 = 0.f;   // a{type}{elem}
    float c00 = 0.f, c01 = 0.f, c10 = 0.f, c11 = 0.f;
    const unsigned short* hin = hb + OFF_IN + lane * 2;
    int p = p0;
    for (; p + 4 <= p1; p += 4) {
        int2 E0 = ed8[p], E1 = ed8[p + 1], E2 = ed8[p + 2], E3 = ed8[p + 3];
        unsigned u0 = *(const unsigned*)(hin + (long)E0.x * K2);
        unsigned u1 = *(const unsigned*)(hin + (long)E1.x * K2);
        unsigned u2 = *(const unsigned*)(hin + (long)E2.x * K2);
        unsigned u3 = *(const unsigned*)(hin + (long)E3.x * K2);
        float2 w0 = decw(E0.y), w1 = decw(E1.y), w2 = decw(E2.y), w3 = decw(E3.y);
        float x0l = bf2f((unsigned short)u0), x0h = bf2f((unsigned short)(u0 >> 16));
        float x1l = bf2f((unsigned short)u1), x1h = bf2f((unsigned short)(u1 >> 16));
        float x2l = bf2f((unsigned short)u2), x2h = bf2f((unsigned short)(u2 >> 16));
        float x3l = bf2f((unsigned short)u3), x3h = bf2f((unsigned short)(u3 >> 16));
        a00 += x0l * w0.x; a01 += x0h * w0.x; a10 += x0l * w0.y; a11 += x0h * w0.y;
        c00 += x1l * w1.x; c01 += x1h * w1.x; c10 += x1l * w1.y; c11 += x1h * w1.y;
        a00 += x2l * w2.x; a01 += x2h * w2.x; a10 += x2l * w2.y; a11 += x2h * w2.y;
        c00 += x3l * w3.x; c01 += x3h * w3.x; c10 += x3l * w3.y; c11 += x3h * w3.y;
    }
    for (; p < p1; ++p) {
        int2 E0 = ed8[p];
        unsigned u0 = *(const unsigned*)(hin + (long)E0.x * K2);
        float2 w0 = decw(E0.y);
        float xl = bf2f((unsigned short)u0), xh = bf2f((unsigned short)(u0 >> 16));
        a00 += xl * w0.x; a01 += xh * w0.x; a10 += xl * w0.y; a11 += xh * w0.y;
    }
    a00 += c00; a01 += c01; a10 += c10; a11 += c11;

    unsigned short* ob = hb + (long)node * K2 + OFFB + lane * 2;
    *(unsigned*)ob       = packbf2(a00, a01);
    *(unsigned*)(ob + D) = packbf2(a10, a11);
}

// ---- GEMM1 via MFMA, 2-phase prefetch dbuf + XCD swizzle -------------------------
#define STAGE_G1(kb, AL, BL) do { \
    _Pragma("unroll") \
    for (int i_ = 0; i_ < 4; ++i_) { \
        int tt = i_ * 256 + t; \
        int r = tt >> 3, s_ = tt & 7, c = s_ ^ (r & 7); \
        GLDS16(hb  + (long)(m0 + r) * K2 + (kb) + c * 8, (AL) + tt * 8); \
        GLDS16(W1b + (long)(n0 + r) * K2 + (kb) + c * 8, (BL) + tt * 8); \
    } } while (0)

__global__ __launch_bounds__(256) void k_gemm1_mfma(const unsigned short* __restrict__ hb,
                                                    const unsigned short* __restrict__ W1b,
                                                    const float* __restrict__ b1,
                                                    unsigned short* __restrict__ h1b,
                                                    float* __restrict__ stats) {
    __shared__ unsigned short Al[2][128 * 64];
    __shared__ unsigned short Bl[2][128 * 64];
    const int t = threadIdx.x;
    const int lane = t & 63;
    const int w = t >> 6;
    const int wr = w >> 1, wc = w & 1;

    const int q = G1_NT / 8, rem = G1_NT % 8;     // 195, 4
    int f = blockIdx.x;
    int xcd = f & 7, posi = f >> 3;
    int logical = (xcd < rem ? xcd * (q + 1) : rem * (q + 1) + (xcd - rem) * q) + posi;
    const int m0 = (logical >> 2) * 128;
    const int n0 = (logical & 3) * 128;

    f32x4 acc[4][4] = {};

    STAGE_G1(0, Al[0], Bl[0]);
    __syncthreads();
    int cur = 0;
    for (int kt = 0; kt < 8; ++kt) {
        if (kt < 7) STAGE_G1((kt + 1) * 64, Al[cur ^ 1], Bl[cur ^ 1]);
        __builtin_amdgcn_sched_barrier(0);
        #pragma unroll
        for (int ks = 0; ks < 2; ++ks) {
            bf16x8 af[4], bfr[4];
            #pragma unroll
            for (int mi = 0; mi < 4; ++mi) {
                int R = wr * 64 + mi * 16 + (lane & 15);
                int sc = (ks * 4 + (lane >> 4)) ^ (R & 7);
                af[mi] = *(const bf16x8*)(Al[cur] + R * 64 + sc * 8);
            }
            #pragma unroll
            for (int nj = 0; nj < 4; ++nj) {
                int R = wc * 64 + nj * 16 + (lane & 15);
                int sc = (ks * 4 + (lane >> 4)) ^ (R & 7);
                bfr[nj] = *(const bf16x8*)(Bl[cur] + R * 64 + sc * 8);
            }
            #pragma unroll
            for (int mi = 0; mi < 4; ++mi)
                #pragma unroll
                for (int nj = 0; nj < 4; ++nj)
                    acc[mi][nj] = __builtin_amdgcn_mfma_f32_16x16x32_bf16(
                        af[mi], bfr[nj], acc[mi][nj], 0, 0, 0);
        }
        __syncthreads();
        cur ^= 1;
    }

    const int cb = n0 + wc * 64;
    float csum[4] = {0.f, 0.f, 0.f, 0.f};
    float csq[4]  = {0.f, 0.f, 0.f, 0.f};
    #pragma unroll
    for (int mi = 0; mi < 4; ++mi) {
        int rbase = m0 + wr * 64 + mi * 16 + (lane >> 4) * 4;
        #pragma unroll
        for (int nj = 0; nj < 4; ++nj) {
            int col = cb + nj * 16 + (lane & 15);
            float bias = b1[col];
            #pragma unroll
            for (int r = 0; r < 4; ++r) {
                int row = rbase + r;
                float v = acc[mi][nj][r] + bias;
                v = v > 0.f ? v : 0.2f * v;
                h1b[(long)row * HID + col] = f2bf(v);
                if (row < N_NODES) {
                    csum[nj] += v;
                    csq[nj]  += v * v;
                }
            }
        }
    }
    #pragma unroll
    for (int nj = 0; nj < 4; ++nj) {
        float s = csum[nj], qq = csq[nj];
        s += __shfl_xor(s, 16); qq += __shfl_xor(qq, 16);
        s += __shfl_xor(s, 32); qq += __shfl_xor(qq, 32);
        if (lane < 16) {
            int col = cb + nj * 16 + lane;
            atomicAdd(&stats[col], s);
            atomicAdd(&stats[HID + col], qq);
        }
    }
}

// ---- fold BN into W2: W2b[j][k] = bf16(W2[j][k]*scale[k]); b2f = b2 + W2@shift ---
__global__ __launch_bounds__(256) void k_fold(const float* __restrict__ stats,
                                              const float* __restrict__ gamma,
                                              const float* __restrict__ beta,
                                              const float* __restrict__ W2,
                                              const float* __restrict__ b2,
                                              unsigned short* __restrict__ W2b,
                                              float* __restrict__ b2f) {
    __shared__ float scale[HID], shift[HID];
    int t = threadIdx.x;
    for (int k = t; k < HID; k += 256) {
        float mu  = stats[k] * (1.f / N_NODES);
        float var = stats[HID + k] * (1.f / N_NODES) - mu * mu;
        var = fmaxf(var, 0.f);
        float sc = gamma[k] * rsqrtf(var + 1e-5f);
        scale[k] = sc;
        shift[k] = beta[k] - mu * sc;
    }
    __syncthreads();
    for (int idx = t; idx < OUT_DIM * HID; idx += 256) {
        int k = idx & 511;
        W2b[idx] = f2bf(W2[idx] * scale[k]);
    }
    if (t < OUT_DIM) {
        float s = b2[t];
        for (int k = 0; k < HID; ++k) s += W2[t * HID + k] * shift[k];
        b2f[t] = s;
    }
}

// ---- head via MFMA, 2-phase prefetch dbuf ----------------------------------------
#define STAGE_HD(kb, AL, BL) do { \
    _Pragma("unroll") \
    for (int i_ = 0; i_ < 4; ++i_) { \
        int tt = i_ * 256 + t; \
        int r = tt >> 3, s_ = tt & 7, c = s_ ^ (r & 7); \
        GLDS16(h1b + (long)(m0 + r) * HID + (kb) + c * 8, (AL) + tt * 8); \
    } \
    _Pragma("unroll") \
    for (int i_ = 0; i_ < 2; ++i_) { \
        int tt = i_ * 256 + t; \
        int r = tt >> 3, s_ = tt & 7, c = s_ ^ (r & 7); \
        GLDS16(W2b + (long)r * HID + (kb) + c * 8, (BL) + tt * 8); \
    } } while (0)

__global__ __launch_bounds__(256) void k_head_mfma(const unsigned short* __restrict__ h1b,
                                                   const unsigned short* __restrict__ W2b,
                                                   const float* __restrict__ b2f,
                                                   const float* __restrict__ Wd,
                                                   const float* __restrict__ bd,
                                                   float* __restrict__ out) {
    __shared__ unsigned short Al[2][128 * 64];   // Al[0] reused as z_lds in epilogue
    __shared__ unsigned short Bl[2][64 * 64];
    __shared__ unsigned short WdL[16 * 64];
    const int t = threadIdx.x;
    const int lane = t & 63;
    const int w = t >> 6;
    const int l15 = lane & 15, hi = lane >> 4;
    const int m0 = blockIdx.x * 128;

    for (int i = t; i < 16 * 64; i += 256) {
        int r = i >> 6, c = i & 63;
        WdL[r * 64 + (((c >> 3) ^ (r & 7)) << 3) + (c & 7)] = f2bf(Wd[i]);
    }

    f32x4 acc[2][4] = {};

    STAGE_HD(0, Al[0], Bl[0]);
    __syncthreads();
    int cur = 0;
    for (int kt = 0; kt < 8; ++kt) {
        if (kt < 7) STAGE_HD((kt + 1) * 64, Al[cur ^ 1], Bl[cur ^ 1]);
        __builtin_amdgcn_sched_barrier(0);
        #pragma unroll
        for (int ks = 0; ks < 2; ++ks) {
            bf16x8 af[2], bfr[4];
            #pragma unroll
            for (int mi = 0; mi < 2; ++mi) {
                int R = w * 32 + mi * 16 + l15;
                int sc = (ks * 4 + hi) ^ (R & 7);
                af[mi] = *(const bf16x8*)(Al[cur] + R * 64 + sc * 8);
            }
            #pragma unroll
            for (int nj = 0; nj < 4; ++nj) {
                int R = nj * 16 + l15;
                int sc = (ks * 4 + hi) ^ (R & 7);
                bfr[nj] = *(const bf16x8*)(Bl[cur] + R * 64 + sc * 8);
            }
            #pragma unroll
            for (int mi = 0; mi < 2; ++mi)
                #pragma unroll
                for (int nj = 0; nj < 4; ++nj)
                    acc[mi][nj] = __builtin_amdgcn_mfma_f32_16x16x32_bf16(
                        af[mi], bfr[nj], acc[mi][nj], 0, 0, 0);
        }
        __syncthreads();
        cur ^= 1;
    }

    float bias[4];
    #pragma unroll
    for (int nj = 0; nj < 4; ++nj) bias[nj] = b2f[nj * 16 + l15];

    float rn[2][4];
    #pragma unroll
    for (int mi = 0; mi < 2; ++mi)
        #pragma unroll
        for (int r = 0; r < 4; ++r) {
            float ss = 0.f;
            #pragma unroll
            for (int nj = 0; nj < 4; ++nj) {
                float v = acc[mi][nj][r] + bias[nj];
                acc[mi][nj][r] = v;
                ss += v * v;
            }
            ss += __shfl_xor(ss, 1); ss += __shfl_xor(ss, 2);
            ss += __shfl_xor(ss, 4); ss += __shfl_xor(ss, 8);
            rn[mi][r] = 1.f / fmaxf(sqrtf(ss), 1e-12f);
        }

    unsigned short* zl = Al[0];
    #pragma unroll
    for (int mi = 0; mi < 2; ++mi)
        #pragma unroll
        for (int r = 0; r < 4; ++r) {
            int lr = w * 32 + mi * 16 + hi * 4 + r;
            int grow = m0 + lr;
            float rnv = rn[mi][r];
            #pragma unroll
            for (int nj = 0; nj < 4; ++nj) {
                int c = nj * 16 + l15;
                float v = acc[mi][nj][r];
                zl[lr * 64 + (((c >> 3) ^ (lr & 7)) << 3) + (c & 7)] = f2bf(v);
                if (grow < N_NODES) out[(long)grow * OUT_DIM + c] = v * rnv;
            }
        }
    __syncthreads();

    f32x4 racc[2] = {};
    #pragma unroll
    for (int mi = 0; mi < 2; ++mi)
        #pragma unroll
        for (int ks = 0; ks < 2; ++ks) {
            int R = w * 32 + mi * 16 + l15;
            int sc = (ks * 4 + hi) ^ (R & 7);
            bf16x8 az = *(const bf16x8*)(zl + R * 64 + sc * 8);
            int scb = (ks * 4 + hi) ^ (l15 & 7);
            bf16x8 bz = *(const bf16x8*)(WdL + l15 * 64 + scb * 8);
            racc[mi] = __builtin_amdgcn_mfma_f32_16x16x32_bf16(az, bz, racc[mi], 0, 0, 0);
        }
    const float bdv = bd[l15];
    #pragma unroll
    for (int mi = 0; mi < 2; ++mi)
        #pragma unroll
        for (int r = 0; r < 4; ++r) {
            int grow = m0 + w * 32 + mi * 16 + hi * 4 + r;
            if (grow < N_NODES)
                out[(long)N_NODES * OUT_DIM + (long)grow * RDIM + l15] = racc[mi][r] + bdv;
        }
}

extern "C" void kernel_launch(void* const* d_in, const int* in_sizes, int n_in,
                              void* d_out, int out_size, void* d_ws, size_t ws_size,
                              hipStream_t stream) {
    const float* feat  = (const float*)d_in[0];
    const int*   ei    = (const int*)  d_in[1];
    const float* ew    = (const float*)d_in[2];
    const int*   et    = (const int*)  d_in[3];
    const float* W1    = (const float*)d_in[4];
    const float* b1    = (const float*)d_in[5];
    const float* gamma = (const float*)d_in[6];
    const float* beta  = (const float*)d_in[7];
    const float* W2    = (const float*)d_in[8];
    const float* b2    = (const float*)d_in[9];
    const float* Wd    = (const float*)d_in[10];
    const float* bd    = (const float*)d_in[11];
    float* out = (float*)d_out;

    float* ws = (float*)d_ws;
    float*          h32   = ws;                                  // [N][48] f32
    unsigned short* hb    = (unsigned short*)(ws + 2400000);     // [MP][512] bf16
    unsigned short* h1b   = hb + (long)MP * K2;                  // [MP][512] bf16
    float*          stats = (float*)(h1b + (long)MP * K2);       // 1024
    unsigned short* W2b   = (unsigned short*)(stats + 1024);     // [64][512] bf16
    float*          b2f   = (float*)(W2b + OUT_DIM * HID);       // 64
    int*            bsum  = (int*)(b2f + 64);                    // 256
    int*            boff  = bsum + 256;                          // 256
    unsigned short* W1b   = (unsigned short*)(boff + 256);       // [512][512] bf16 (own slot)

    // CSR scratch aliased onto h1b region (dead once gathers finish)
    int*    deg    = (int*)h1b;
    int*    rowptr = deg + 50008;
    int*    cur    = rowptr + 50008;
    int2*   ed8    = (int2*)(cur + 50008);     // 8B-aligned (150024 ints offset)
    int*    pos    = (int*)(ed8 + NEDGE);

    k_init<<<(MP * IN_DIM + 255) / 256, 256, 0, stream>>>(feat, W1, h32, hb, W1b, stats, deg);
    k_hist<<<(NEDGE + 255) / 256, 256, 0, stream>>>(ei, deg);
    k_scanA<<<SCAN_B, 256, 0, stream>>>(deg, bsum);
    k_scanB<<<1, 256, 0, stream>>>(bsum, boff);
    k_scanC<<<SCAN_B, 256, 0, stream>>>(deg, boff, rowptr, cur);
    k_pos <<<(NEDGE + 255) / 256, 256, 0, stream>>>(ei, cur, pos);
    k_scat<<<(NEDGE + 255) / 256, 256, 0, stream>>>(ei, ew, et, pos, ed8);

    k_gather<16,  0, 16, 16, 16, 1, true ><<<(N_NODES + 15) / 16, 256, 0, stream>>>(rowptr, ed8, h32, hb);
    k_gather<32, 16, -1, 48, 32, 1, false><<<(N_NODES + 7)  / 8,  256, 0, stream>>>(rowptr, ed8, h32, hb);
    k_gather_bf<64,  48, 112, 32><<<(N_NODES + 7) / 8, 256, 0, stream>>>(rowptr, ed8, hb);
    k_gather_bf<128, 112, 240, 64><<<(N_NODES + 3) / 4, 256, 0, stream>>>(rowptr, ed8, hb);

    k_gemm1_mfma<<<G1_NT, 256, 0, stream>>>(hb, W1b, b1, h1b, stats);

    k_fold<<<1, 256, 0, stream>>>(stats, gamma, beta, W2, b2, W2b, b2f);

    k_head_mfma<<<MP / 128, 256, 0, stream>>>(h1b, W2b, b2f, Wd, bd, out);
}

// Round 8
// 333.337 us; speedup vs baseline: 9.4545x; 1.2406x over previous
//
#include <hip/hip_runtime.h>

#define N_NODES   50000
#define MP        50048          // rows padded to 128
#define IN_DIM    16
#define CONCAT    496
#define K2        512            // padded K for GEMM1
#define HID       512
#define OUT_DIM   64
#define RDIM      16
#define NEDGE     800000
#define H32S      48             // h32 row stride (feature 0..15, L1 out 16..47)
#define SCAN_B    196            // ceil(50000/256)
#define G1_NT     ((MP / 128) * 4)   // 1564 gemm1 tiles

typedef __attribute__((ext_vector_type(8))) short bf16x8;
typedef __attribute__((ext_vector_type(4))) float f32x4;

static __device__ __forceinline__ unsigned short f2bf(float x) {
    union { float f; unsigned u; } v; v.f = x;
    unsigned r = v.u + 0x7fff + ((v.u >> 16) & 1);
    return (unsigned short)(r >> 16);
}
static __device__ __forceinline__ float bf2f(unsigned short b) {
    union { unsigned u; float f; } v; v.u = ((unsigned)b) << 16; return v.f;
}
static __device__ __forceinline__ unsigned packbf2(float a, float b) {
    return (unsigned)f2bf(a) | ((unsigned)f2bf(b) << 16);
}
static __device__ __forceinline__ float2 decw(int wbi) {
    unsigned wb = (unsigned)wbi;
    float w = __uint_as_float(wb & 0x7fffffffu);
    return (wb >> 31) ? make_float2(0.f, w) : make_float2(w, 0.f);
}

#define GLDS16(gp, lp) \
    __builtin_amdgcn_global_load_lds((const __attribute__((address_space(1))) unsigned int*)(gp), \
                                     (__attribute__((address_space(3))) unsigned int*)(lp), 16, 0, 0)

// ---- init: feature -> h32/hb; zero pads/stats/deg; W1 -> bf16 (fused cvtw) -------
__global__ __launch_bounds__(256) void k_init(const float* __restrict__ feat,
                                              const float* __restrict__ W1,
                                              float* __restrict__ h32,
                                              unsigned short* __restrict__ hb,
                                              unsigned short* __restrict__ W1b,
                                              float* __restrict__ stats,
                                              int* __restrict__ deg) {
    int idx = blockIdx.x * blockDim.x + threadIdx.x;
    if (idx < 1024) stats[idx] = 0.f;
    if (idx < N_NODES) deg[idx] = 0;
    if (idx < HID * K2) {                          // W1 -> bf16, K-padded
        int n = idx >> 9, k = idx & 511;
        W1b[idx] = (k < CONCAT) ? f2bf(W1[n * CONCAT + k]) : (unsigned short)0;
    }
    if (idx < (MP - N_NODES) * K2) {               // zero padded rows of hb
        int r = N_NODES + (idx >> 9), c = idx & 511;
        hb[(long)r * K2 + c] = 0;
    }
    if (idx >= MP * IN_DIM) return;
    int n = idx >> 4, c = idx & 15;
    hb[(long)n * K2 + CONCAT + c] = 0;             // K pad cols 496..511
    if (n < N_NODES) {
        float x = feat[idx];
        h32[(long)n * H32S + c] = x;
        hb[(long)n * K2 + c] = f2bf(x);
    }
}

// ---- CSR build: hist also emits per-edge rank within its dst bucket --------------
__global__ __launch_bounds__(256) void k_hist(const int* __restrict__ ei,
                                              int* __restrict__ deg,
                                              int* __restrict__ rank) {
    int e = blockIdx.x * blockDim.x + threadIdx.x;
    if (e < NEDGE) rank[e] = atomicAdd(&deg[ei[NEDGE + e]], 1);
}

__global__ __launch_bounds__(256) void k_scanA(const int* __restrict__ deg,
                                               int* __restrict__ bsum) {
    __shared__ int red[256];
    int t = threadIdx.x;
    int i = blockIdx.x * 256 + t;
    red[t] = (i < N_NODES) ? deg[i] : 0;
    __syncthreads();
    for (int d = 128; d > 0; d >>= 1) {
        if (t < d) red[t] += red[t + d];
        __syncthreads();
    }
    if (t == 0) bsum[blockIdx.x] = red[0];
}

__global__ __launch_bounds__(256) void k_scanB(const int* __restrict__ bsum,
                                               int* __restrict__ boff) {
    __shared__ int s[256];
    int t = threadIdx.x;
    s[t] = (t < SCAN_B) ? bsum[t] : 0;
    __syncthreads();
    for (int d = 1; d < 256; d <<= 1) {
        int v = (t >= d) ? s[t - d] : 0;
        __syncthreads();
        s[t] += v;
        __syncthreads();
    }
    boff[t] = (t > 0) ? s[t - 1] : 0;
}

__global__ __launch_bounds__(256) void k_scanC(const int* __restrict__ deg,
                                               const int* __restrict__ boff,
                                               int* __restrict__ rowptr) {
    __shared__ int s[256];
    int t = threadIdx.x;
    int i = blockIdx.x * 256 + t;
    int v = (i < N_NODES) ? deg[i] : 0;
    s[t] = v;
    __syncthreads();
    for (int d = 1; d < 256; d <<= 1) {
        int x = (t >= d) ? s[t - d] : 0;
        __syncthreads();
        s[t] += x;
        __syncthreads();
    }
    int excl = s[t] - v + boff[blockIdx.x];
    if (i < N_NODES) rowptr[i] = excl;
    if (i == N_NODES - 1) rowptr[N_NODES] = excl + v;
}

// ---- edge scatter: pos = rowptr[dst] + rank[e]; 8B packed record -----------------
__global__ __launch_bounds__(256) void k_scat(const int* __restrict__ ei,
                                              const float* __restrict__ ew,
                                              const int* __restrict__ et,
                                              const int* __restrict__ rank,
                                              const int* __restrict__ rowptr,
                                              int2* __restrict__ ed8) {
    int e = blockIdx.x * blockDim.x + threadIdx.x;
    if (e >= NEDGE) return;
    int dst = ei[NEDGE + e];
    unsigned wb = (__float_as_uint(ew[e]) & 0x7fffffffu) | ((unsigned)et[e] << 31);
    ed8[rowptr[dst] + rank[e]] = make_int2(ei[e], (int)wb);
}

// ---- gather (f32 input): G lanes per dst, V floats per lane; unroll-4 ------------
template<int D, int OFF_IN, int OFF32, int OFFB, int G, int V, bool W32>
__global__ __launch_bounds__(256) void k_gather(const int* __restrict__ rowptr,
                                                const int2* __restrict__ ed8,
                                                float* __restrict__ h32,
                                                unsigned short* __restrict__ hb) {
    const int NPB = 256 / G;
    int node = blockIdx.x * NPB + threadIdx.x / G;
    if (node >= N_NODES) return;
    int lane = threadIdx.x % G;
    int p0 = rowptr[node], p1 = rowptr[node + 1];
    float a0[V] = {}, a1[V] = {}, c0[V] = {}, c1[V] = {};
    const float* hin = h32 + OFF_IN + lane * V;
    int p = p0;
    for (; p + 4 <= p1; p += 4) {
        int2 E0 = ed8[p], E1 = ed8[p + 1], E2 = ed8[p + 2], E3 = ed8[p + 3];
        const float* R0 = hin + (long)E0.x * H32S;
        const float* R1 = hin + (long)E1.x * H32S;
        const float* R2 = hin + (long)E2.x * H32S;
        const float* R3 = hin + (long)E3.x * H32S;
        float x0[V], x1[V], x2[V], x3[V];
        #pragma unroll
        for (int v = 0; v < V; ++v) { x0[v] = R0[v]; x1[v] = R1[v]; x2[v] = R2[v]; x3[v] = R3[v]; }
        float2 w0 = decw(E0.y), w1 = decw(E1.y), w2 = decw(E2.y), w3 = decw(E3.y);
        #pragma unroll
        for (int v = 0; v < V; ++v) {
            a0[v] += x0[v] * w0.x; a1[v] += x0[v] * w0.y;
            c0[v] += x1[v] * w1.x; c1[v] += x1[v] * w1.y;
            a0[v] += x2[v] * w2.x; a1[v] += x2[v] * w2.y;
            c0[v] += x3[v] * w3.x; c1[v] += x3[v] * w3.y;
        }
    }
    for (; p < p1; ++p) {
        int2 E0 = ed8[p];
        const float* R0 = hin + (long)E0.x * H32S;
        float2 w0 = decw(E0.y);
        #pragma unroll
        for (int v = 0; v < V; ++v) {
            float x = R0[v];
            a0[v] += x * w0.x; a1[v] += x * w0.y;
        }
    }
    #pragma unroll
    for (int v = 0; v < V; ++v) { a0[v] += c0[v]; a1[v] += c1[v]; }

    if (W32) {
        float* o = h32 + (long)node * H32S + OFF32 + lane * V;
        #pragma unroll
        for (int v = 0; v < V; ++v) { o[v] = a0[v]; o[v + D] = a1[v]; }
    }
    unsigned short* ob = hb + (long)node * K2 + OFFB + lane * V;
    #pragma unroll
    for (int v = 0; v < V; ++v) { ob[v] = f2bf(a0[v]); ob[v + D] = f2bf(a1[v]); }
}

// ---- gather (bf16 input from hb): V==2, 4B packed loads/stores; unroll-4 ---------
template<int D, int OFF_IN, int OFFB, int G>
__global__ __launch_bounds__(256) void k_gather_bf(const int* __restrict__ rowptr,
                                                   const int2* __restrict__ ed8,
                                                   unsigned short* __restrict__ hb) {
    const int NPB = 256 / G;
    int node = blockIdx.x * NPB + threadIdx.x / G;
    if (node >= N_NODES) return;
    int lane = threadIdx.x % G;
    int p0 = rowptr[node], p1 = rowptr[node + 1];
    float a00 = 0.f, a01 = 0.f, a10 = 0.f, a11 = 0.f;
    float c00 = 0.f, c01 = 0.f, c10 = 0.f, c11 = 0.f;
    const unsigned short* hin = hb + OFF_IN + lane * 2;
    int p = p0;
    for (; p + 4 <= p1; p += 4) {
        int2 E0 = ed8[p], E1 = ed8[p + 1], E2 = ed8[p + 2], E3 = ed8[p + 3];
        unsigned u0 = *(const unsigned*)(hin + (long)E0.x * K2);
        unsigned u1 = *(const unsigned*)(hin + (long)E1.x * K2);
        unsigned u2 = *(const unsigned*)(hin + (long)E2.x * K2);
        unsigned u3 = *(const unsigned*)(hin + (long)E3.x * K2);
        float2 w0 = decw(E0.y), w1 = decw(E1.y), w2 = decw(E2.y), w3 = decw(E3.y);
        float x0l = bf2f((unsigned short)u0), x0h = bf2f((unsigned short)(u0 >> 16));
        float x1l = bf2f((unsigned short)u1), x1h = bf2f((unsigned short)(u1 >> 16));
        float x2l = bf2f((unsigned short)u2), x2h = bf2f((unsigned short)(u2 >> 16));
        float x3l = bf2f((unsigned short)u3), x3h = bf2f((unsigned short)(u3 >> 16));
        a00 += x0l * w0.x; a01 += x0h * w0.x; a10 += x0l * w0.y; a11 += x0h * w0.y;
        c00 += x1l * w1.x; c01 += x1h * w1.x; c10 += x1l * w1.y; c11 += x1h * w1.y;
        a00 += x2l * w2.x; a01 += x2h * w2.x; a10 += x2l * w2.y; a11 += x2h * w2.y;
        c00 += x3l * w3.x; c01 += x3h * w3.x; c10 += x3l * w3.y; c11 += x3h * w3.y;
    }
    for (; p < p1; ++p) {
        int2 E0 = ed8[p];
        unsigned u0 = *(const unsigned*)(hin + (long)E0.x * K2);
        float2 w0 = decw(E0.y);
        float xl = bf2f((unsigned short)u0), xh = bf2f((unsigned short)(u0 >> 16));
        a00 += xl * w0.x; a01 += xh * w0.x; a10 += xl * w0.y; a11 += xh * w0.y;
    }
    a00 += c00; a01 += c01; a10 += c10; a11 += c11;

    unsigned short* ob = hb + (long)node * K2 + OFFB + lane * 2;
    *(unsigned*)ob       = packbf2(a00, a01);
    *(unsigned*)(ob + D) = packbf2(a10, a11);
}

// ---- GEMM1 via MFMA, 2-phase prefetch dbuf + XCD swizzle -------------------------
#define STAGE_G1(kb, AL, BL) do { \
    _Pragma("unroll") \
    for (int i_ = 0; i_ < 4; ++i_) { \
        int tt = i_ * 256 + t; \
        int r = tt >> 3, s_ = tt & 7, c = s_ ^ (r & 7); \
        GLDS16(hb  + (long)(m0 + r) * K2 + (kb) + c * 8, (AL) + tt * 8); \
        GLDS16(W1b + (long)(n0 + r) * K2 + (kb) + c * 8, (BL) + tt * 8); \
    } } while (0)

__global__ __launch_bounds__(256) void k_gemm1_mfma(const unsigned short* __restrict__ hb,
                                                    const unsigned short* __restrict__ W1b,
                                                    const float* __restrict__ b1,
                                                    unsigned short* __restrict__ h1b,
                                                    float* __restrict__ stats) {
    __shared__ unsigned short Al[2][128 * 64];
    __shared__ unsigned short Bl[2][128 * 64];
    const int t = threadIdx.x;
    const int lane = t & 63;
    const int w = t >> 6;
    const int wr = w >> 1, wc = w & 1;

    const int q = G1_NT / 8, rem = G1_NT % 8;     // 195, 4
    int f = blockIdx.x;
    int xcd = f & 7, posi = f >> 3;
    int logical = (xcd < rem ? xcd * (q + 1) : rem * (q + 1) + (xcd - rem) * q) + posi;
    const int m0 = (logical >> 2) * 128;
    const int n0 = (logical & 3) * 128;

    f32x4 acc[4][4] = {};

    STAGE_G1(0, Al[0], Bl[0]);
    __syncthreads();
    int cur = 0;
    for (int kt = 0; kt < 8; ++kt) {
        if (kt < 7) STAGE_G1((kt + 1) * 64, Al[cur ^ 1], Bl[cur ^ 1]);
        __builtin_amdgcn_sched_barrier(0);
        #pragma unroll
        for (int ks = 0; ks < 2; ++ks) {
            bf16x8 af[4], bfr[4];
            #pragma unroll
            for (int mi = 0; mi < 4; ++mi) {
                int R = wr * 64 + mi * 16 + (lane & 15);
                int sc = (ks * 4 + (lane >> 4)) ^ (R & 7);
                af[mi] = *(const bf16x8*)(Al[cur] + R * 64 + sc * 8);
            }
            #pragma unroll
            for (int nj = 0; nj < 4; ++nj) {
                int R = wc * 64 + nj * 16 + (lane & 15);
                int sc = (ks * 4 + (lane >> 4)) ^ (R & 7);
                bfr[nj] = *(const bf16x8*)(Bl[cur] + R * 64 + sc * 8);
            }
            #pragma unroll
            for (int mi = 0; mi < 4; ++mi)
                #pragma unroll
                for (int nj = 0; nj < 4; ++nj)
                    acc[mi][nj] = __builtin_amdgcn_mfma_f32_16x16x32_bf16(
                        af[mi], bfr[nj], acc[mi][nj], 0, 0, 0);
        }
        __syncthreads();
        cur ^= 1;
    }

    const int cb = n0 + wc * 64;
    float csum[4] = {0.f, 0.f, 0.f, 0.f};
    float csq[4]  = {0.f, 0.f, 0.f, 0.f};
    #pragma unroll
    for (int mi = 0; mi < 4; ++mi) {
        int rbase = m0 + wr * 64 + mi * 16 + (lane >> 4) * 4;
        #pragma unroll
        for (int nj = 0; nj < 4; ++nj) {
            int col = cb + nj * 16 + (lane & 15);
            float bias = b1[col];
            #pragma unroll
            for (int r = 0; r < 4; ++r) {
                int row = rbase + r;
                float v = acc[mi][nj][r] + bias;
                v = v > 0.f ? v : 0.2f * v;
                h1b[(long)row * HID + col] = f2bf(v);
                if (row < N_NODES) {
                    csum[nj] += v;
                    csq[nj]  += v * v;
                }
            }
        }
    }
    #pragma unroll
    for (int nj = 0; nj < 4; ++nj) {
        float s = csum[nj], qq = csq[nj];
        s += __shfl_xor(s, 16); qq += __shfl_xor(qq, 16);
        s += __shfl_xor(s, 32); qq += __shfl_xor(qq, 32);
        if (lane < 16) {
            int col = cb + nj * 16 + lane;
            atomicAdd(&stats[col], s);
            atomicAdd(&stats[HID + col], qq);
        }
    }
}

// ---- fold BN into W2 (parallel: one block per W2 row) ----------------------------
__global__ __launch_bounds__(256) void k_fold2(const float* __restrict__ stats,
                                               const float* __restrict__ gamma,
                                               const float* __restrict__ beta,
                                               const float* __restrict__ W2,
                                               const float* __restrict__ b2,
                                               unsigned short* __restrict__ W2b,
                                               float* __restrict__ b2f) {
    __shared__ float scale[HID], shift[HID];
    __shared__ float red[4];
    const int t = threadIdx.x;
    const int j = blockIdx.x;                     // 0..63
    #pragma unroll
    for (int kk = 0; kk < 2; ++kk) {
        int k = t + kk * 256;
        float mu  = stats[k] * (1.f / N_NODES);
        float var = stats[HID + k] * (1.f / N_NODES) - mu * mu;
        var = fmaxf(var, 0.f);
        float sc = gamma[k] * rsqrtf(var + 1e-5f);
        scale[k] = sc;
        shift[k] = beta[k] - mu * sc;
    }
    __syncthreads();
    float part = 0.f;
    #pragma unroll
    for (int kk = 0; kk < 2; ++kk) {
        int k = t + kk * 256;
        float wv = W2[j * HID + k];
        W2b[j * HID + k] = f2bf(wv * scale[k]);
        part += wv * shift[k];
    }
    part += __shfl_xor(part, 1);  part += __shfl_xor(part, 2);
    part += __shfl_xor(part, 4);  part += __shfl_xor(part, 8);
    part += __shfl_xor(part, 16); part += __shfl_xor(part, 32);
    if ((t & 63) == 0) red[t >> 6] = part;
    __syncthreads();
    if (t == 0) b2f[j] = b2[j] + red[0] + red[1] + red[2] + red[3];
}

// ---- head via MFMA, 2-phase prefetch dbuf ----------------------------------------
#define STAGE_HD(kb, AL, BL) do { \
    _Pragma("unroll") \
    for (int i_ = 0; i_ < 4; ++i_) { \
        int tt = i_ * 256 + t; \
        int r = tt >> 3, s_ = tt & 7, c = s_ ^ (r & 7); \
        GLDS16(h1b + (long)(m0 + r) * HID + (kb) + c * 8, (AL) + tt * 8); \
    } \
    _Pragma("unroll") \
    for (int i_ = 0; i_ < 2; ++i_) { \
        int tt = i_ * 256 + t; \
        int r = tt >> 3, s_ = tt & 7, c = s_ ^ (r & 7); \
        GLDS16(W2b + (long)r * HID + (kb) + c * 8, (BL) + tt * 8); \
    } } while (0)

__global__ __launch_bounds__(256) void k_head_mfma(const unsigned short* __restrict__ h1b,
                                                   const unsigned short* __restrict__ W2b,
                                                   const float* __restrict__ b2f,
                                                   const float* __restrict__ Wd,
                                                   const float* __restrict__ bd,
                                                   float* __restrict__ out) {
    __shared__ unsigned short Al[2][128 * 64];   // Al[0] reused as z_lds in epilogue
    __shared__ unsigned short Bl[2][64 * 64];
    __shared__ unsigned short WdL[16 * 64];
    const int t = threadIdx.x;
    const int lane = t & 63;
    const int w = t >> 6;
    const int l15 = lane & 15, hi = lane >> 4;
    const int m0 = blockIdx.x * 128;

    for (int i = t; i < 16 * 64; i += 256) {
        int r = i >> 6, c = i & 63;
        WdL[r * 64 + (((c >> 3) ^ (r & 7)) << 3) + (c & 7)] = f2bf(Wd[i]);
    }

    f32x4 acc[2][4] = {};

    STAGE_HD(0, Al[0], Bl[0]);
    __syncthreads();
    int cur = 0;
    for (int kt = 0; kt < 8; ++kt) {
        if (kt < 7) STAGE_HD((kt + 1) * 64, Al[cur ^ 1], Bl[cur ^ 1]);
        __builtin_amdgcn_sched_barrier(0);
        #pragma unroll
        for (int ks = 0; ks < 2; ++ks) {
            bf16x8 af[2], bfr[4];
            #pragma unroll
            for (int mi = 0; mi < 2; ++mi) {
                int R = w * 32 + mi * 16 + l15;
                int sc = (ks * 4 + hi) ^ (R & 7);
                af[mi] = *(const bf16x8*)(Al[cur] + R * 64 + sc * 8);
            }
            #pragma unroll
            for (int nj = 0; nj < 4; ++nj) {
                int R = nj * 16 + l15;
                int sc = (ks * 4 + hi) ^ (R & 7);
                bfr[nj] = *(const bf16x8*)(Bl[cur] + R * 64 + sc * 8);
            }
            #pragma unroll
            for (int mi = 0; mi < 2; ++mi)
                #pragma unroll
                for (int nj = 0; nj < 4; ++nj)
                    acc[mi][nj] = __builtin_amdgcn_mfma_f32_16x16x32_bf16(
                        af[mi], bfr[nj], acc[mi][nj], 0, 0, 0);
        }
        __syncthreads();
        cur ^= 1;
    }

    float bias[4];
    #pragma unroll
    for (int nj = 0; nj < 4; ++nj) bias[nj] = b2f[nj * 16 + l15];

    float rn[2][4];
    #pragma unroll
    for (int mi = 0; mi < 2; ++mi)
        #pragma unroll
        for (int r = 0; r < 4; ++r) {
            float ss = 0.f;
            #pragma unroll
            for (int nj = 0; nj < 4; ++nj) {
                float v = acc[mi][nj][r] + bias[nj];
                acc[mi][nj][r] = v;
                ss += v * v;
            }
            ss += __shfl_xor(ss, 1); ss += __shfl_xor(ss, 2);
            ss += __shfl_xor(ss, 4); ss += __shfl_xor(ss, 8);
            rn[mi][r] = 1.f / fmaxf(sqrtf(ss), 1e-12f);
        }

    unsigned short* zl = Al[0];
    #pragma unroll
    for (int mi = 0; mi < 2; ++mi)
        #pragma unroll
        for (int r = 0; r < 4; ++r) {
            int lr = w * 32 + mi * 16 + hi * 4 + r;
            int grow = m0 + lr;
            float rnv = rn[mi][r];
            #pragma unroll
            for (int nj = 0; nj < 4; ++nj) {
                int c = nj * 16 + l15;
                float v = acc[mi][nj][r];
                zl[lr * 64 + (((c >> 3) ^ (lr & 7)) << 3) + (c & 7)] = f2bf(v);
                if (grow < N_NODES) out[(long)grow * OUT_DIM + c] = v * rnv;
            }
        }
    __syncthreads();

    f32x4 racc[2] = {};
    #pragma unroll
    for (int mi = 0; mi < 2; ++mi)
        #pragma unroll
        for (int ks = 0; ks < 2; ++ks) {
            int R = w * 32 + mi * 16 + l15;
            int sc = (ks * 4 + hi) ^ (R & 7);
            bf16x8 az = *(const bf16x8*)(zl + R * 64 + sc * 8);
            int scb = (ks * 4 + hi) ^ (l15 & 7);
            bf16x8 bz = *(const bf16x8*)(WdL + l15 * 64 + scb * 8);
            racc[mi] = __builtin_amdgcn_mfma_f32_16x16x32_bf16(az, bz, racc[mi], 0, 0, 0);
        }
    const float bdv = bd[l15];
    #pragma unroll
    for (int mi = 0; mi < 2; ++mi)
        #pragma unroll
        for (int r = 0; r < 4; ++r) {
            int grow = m0 + w * 32 + mi * 16 + hi * 4 + r;
            if (grow < N_NODES)
                out[(long)N_NODES * OUT_DIM + (long)grow * RDIM + l15] = racc[mi][r] + bdv;
        }
}

extern "C" void kernel_launch(void* const* d_in, const int* in_sizes, int n_in,
                              void* d_out, int out_size, void* d_ws, size_t ws_size,
                              hipStream_t stream) {
    const float* feat  = (const float*)d_in[0];
    const int*   ei    = (const int*)  d_in[1];
    const float* ew    = (const float*)d_in[2];
    const int*   et    = (const int*)  d_in[3];
    const float* W1    = (const float*)d_in[4];
    const float* b1    = (const float*)d_in[5];
    const float* gamma = (const float*)d_in[6];
    const float* beta  = (const float*)d_in[7];
    const float* W2    = (const float*)d_in[8];
    const float* b2    = (const float*)d_in[9];
    const float* Wd    = (const float*)d_in[10];
    const float* bd    = (const float*)d_in[11];
    float* out = (float*)d_out;

    float* ws = (float*)d_ws;
    float*          h32   = ws;                                  // [N][48] f32
    unsigned short* hb    = (unsigned short*)(ws + 2400000);     // [MP][512] bf16
    unsigned short* h1b   = hb + (long)MP * K2;                  // [MP][512] bf16
    float*          stats = (float*)(h1b + (long)MP * K2);       // 1024
    unsigned short* W2b   = (unsigned short*)(stats + 1024);     // [64][512] bf16
    float*          b2f   = (float*)(W2b + OUT_DIM * HID);       // 64
    int*            bsum  = (int*)(b2f + 64);                    // 256
    int*            boff  = bsum + 256;                          // 256
    unsigned short* W1b   = (unsigned short*)(boff + 256);       // [512][512] bf16 (own slot)

    // CSR scratch aliased onto h1b region (dead once gathers finish)
    int*    deg    = (int*)h1b;
    int*    rowptr = deg + 50008;
    int2*   ed8    = (int2*)(rowptr + 50008);    // 8B aligned (100016 ints offset)
    int*    rank   = (int*)(ed8 + NEDGE);

    k_init<<<(MP * IN_DIM + 255) / 256, 256, 0, stream>>>(feat, W1, h32, hb, W1b, stats, deg);
    k_hist<<<(NEDGE + 255) / 256, 256, 0, stream>>>(ei, deg, rank);
    k_scanA<<<SCAN_B, 256, 0, stream>>>(deg, bsum);
    k_scanB<<<1, 256, 0, stream>>>(bsum, boff);
    k_scanC<<<SCAN_B, 256, 0, stream>>>(deg, boff, rowptr);
    k_scat<<<(NEDGE + 255) / 256, 256, 0, stream>>>(ei, ew, et, rank, rowptr, ed8);

    k_gather<16,  0, 16, 16, 16, 1, true ><<<(N_NODES + 15) / 16, 256, 0, stream>>>(rowptr, ed8, h32, hb);
    k_gather<32, 16, -1, 48, 32, 1, false><<<(N_NODES + 7)  / 8,  256, 0, stream>>>(rowptr, ed8, h32, hb);
    k_gather_bf<64,  48, 112, 32><<<(N_NODES + 7) / 8, 256, 0, stream>>>(rowptr, ed8, hb);
    k_gather_bf<128, 112, 240, 64><<<(N_NODES + 3) / 4, 256, 0, stream>>>(rowptr, ed8, hb);

    k_gemm1_mfma<<<G1_NT, 256, 0, stream>>>(hb, W1b, b1, h1b, stats);

    k_fold2<<<OUT_DIM, 256, 0, stream>>>(stats, gamma, beta, W2, b2, W2b, b2f);

    k_head_mfma<<<MP / 128, 256, 0, stream>>>(h1b, W2b, b2f, Wd, bd, out);
}